// Round 12
// baseline (130.586 us; speedup 1.0000x reference)
//
#include <hip/hip_runtime.h>

// ---------------------------------------------------------------------------
// MultiHeadedAttention: B=4, S=2048, D=512, H=8, DK=64
// 5 dispatches (round-11 + flash PV via 16x16x16 MFMA, P kept in registers):
//   prep       : WT[n][k] bf16 pre-swizzled (granule^(n&7)) for Wq,Wk,Wv,Wo
//                ++ lex partials
//   qkv (z<3)  : BN=128 gemm, XCD-chunked swizzle
//       (z=3)  : vbar1 = exp(lex-from-part) . v partials + psum partials
//   vbar2      : vbar = (t1@Wv)/tot + bv
//   flash      : 4 waves x 32q; swapped QK^T; P=exp2(st) packed in-register
//                as the A-operand of mfma_f32_16x16x16bf16_1k (no P LDS
//                round-trip); lsum via MFMA vs bf16 mask row; gl_lds dbuf K/V
//   gemmO      : out = Cc@Wo + bo (f32), BN=128, XCD swizzle
// ---------------------------------------------------------------------------

typedef __attribute__((ext_vector_type(4))) float f32x4;
typedef __attribute__((ext_vector_type(8))) short s16x8;
typedef __attribute__((ext_vector_type(4))) short s16x4;

#define QSCALE 0.18033688011112042f  // 0.125 * log2(e)
#define MFMA16(a, b, c) __builtin_amdgcn_mfma_f32_16x16x16bf16_1k(a, b, c, 0, 0, 0)

__device__ inline short f2bf(float f) {
  __bf16 h = (__bf16)f;
  return __builtin_bit_cast(short, h);
}
__device__ inline float fast_exp2(float x) {
#if __has_builtin(__builtin_amdgcn_exp2f)
  return __builtin_amdgcn_exp2f(x);
#else
  return exp2f(x);
#endif
}
__device__ inline void gl_lds16(const void* g, void* l) {
  __builtin_amdgcn_global_load_lds(
      (const __attribute__((address_space(1))) void*)g,
      (__attribute__((address_space(3))) void*)l, 16, 0, 0);
}

// ---------------------------------------------------------------------------
// prep: blocks 0..1023 = weight transpose + swizzle; 1024..1151 = lex partials
// ---------------------------------------------------------------------------
struct PrepArgs {
  const float* W[4];
  short* WT[4];
  const float* Lex;
  const float* Wl;
  float* part;
};

__global__ __launch_bounds__(256) void prep(PrepArgs pa) {
  const int blk = blockIdx.x;
  if (blk < 1024) {
    const int z = blk >> 8, tt = blk & 255;
    const float* __restrict__ W = pa.W[z];
    short* __restrict__ WT = pa.WT[z];
    const int n0 = (tt & 15) * 32, k0 = (tt >> 4) * 32;
    const int tx = threadIdx.x & 31, ty = threadIdx.x >> 5;
    __shared__ float Tl[32][33];
#pragma unroll
    for (int j = 0; j < 4; ++j)
      Tl[ty + j * 8][tx] = W[(size_t)(k0 + ty + j * 8) * 512 + n0 + tx];
    __syncthreads();
#pragma unroll
    for (int j = 0; j < 4; ++j) {
      int n = n0 + ty + j * 8, k = k0 + tx;
      int kg = k >> 3;
      int kswz = (((kg & ~7) | ((kg & 7) ^ (n & 7))) << 3) | (k & 7);
      WT[(size_t)n * 512 + kswz] = f2bf(Tl[tx][ty + j * 8]);
    }
  } else {
    const int jb = blk - 1024;
    const int j = (jb & 7) * 256 + threadIdx.x;
    const int sb = jb >> 3, s0 = sb * 128;
    __shared__ float Lsh[4][128];
#pragma unroll
    for (int l = 0; l < 2; ++l) {
      int idx = threadIdx.x + l * 256;
      Lsh[idx >> 7][idx & 127] = pa.Lex[(idx >> 7) * 2048 + s0 + (idx & 127)];
    }
    __syncthreads();
    float a0 = 0.f, a1 = 0.f, a2 = 0.f, a3 = 0.f;
#pragma unroll 4
    for (int si = 0; si < 128; ++si) {
      float w = pa.Wl[(size_t)(s0 + si) * 2048 + j];
      a0 += Lsh[0][si] * w; a1 += Lsh[1][si] * w;
      a2 += Lsh[2][si] * w; a3 += Lsh[3][si] * w;
    }
    pa.part[(sb * 4 + 0) * 2048 + j] = a0;
    pa.part[(sb * 4 + 1) * 2048 + j] = a1;
    pa.part[(sb * 4 + 2) * 2048 + j] = a2;
    pa.part[(sb * 4 + 3) * 2048 + j] = a3;
  }
}

// ---------------------------------------------------------------------------
// vbar2: vbar[b,j] = (t1_b @ Wv)[j]/tot + bv[j].  grid(4,8) x 256
// ---------------------------------------------------------------------------
__global__ __launch_bounds__(256) void vbar2(const float* __restrict__ t1p,
                                             const float* __restrict__ psp,
                                             const float* __restrict__ Wv,
                                             const float* __restrict__ bv,
                                             float* __restrict__ vbar) {
  const int b = blockIdx.x, jb = blockIdx.y, tid = threadIdx.x;
  const int jl = tid & 63, sp = tid >> 6;
  const int j = jb * 64 + jl;
  __shared__ float t1[512];
  __shared__ float red[4][64];
#pragma unroll
  for (int l = 0; l < 2; ++l) {
    int idx = tid + l * 256;
    float s = 0.f;
#pragma unroll 8
    for (int p = 0; p < 64; ++p) s += t1p[(size_t)(b * 64 + p) * 512 + idx];
    t1[idx] = s;
  }
  __syncthreads();
  float a = 0.f;
#pragma unroll 4
  for (int d = sp * 128; d < sp * 128 + 128; ++d) a += t1[d] * Wv[(size_t)d * 512 + j];
  red[sp][jl] = a;
  __syncthreads();
  if (sp == 0) {
    float tot = 0.f;
#pragma unroll 8
    for (int p = 0; p < 64; ++p) tot += psp[b * 64 + p];
    float s = red[0][jl] + red[1][jl] + red[2][jl] + red[3][jl];
    vbar[b * 512 + j] = s / tot + bv[j];
  }
}

// ---------------------------------------------------------------------------
// GEMM: C = X@W + bias, BM=64, BN=128, BK=64; 4 waves 2x2, each 32x64.
// XCD-chunked block swizzle (bijective on [0,512)).
// z<3: tensors; z==3 (QKV launch only): vbar1 partials.
// mode 0: bf16 row-major; 1: bf16 V^T (mask-zeroed); 2: f32 row-major
// ---------------------------------------------------------------------------
struct GemmArgs {
  const void* X[3];
  const short* WT[3];
  const float* bias[3];
  void* C[3];
  float oscale[3];
  int mode[3];
  const int* mask;
  const float* part;   // vbar1 inputs (QKV launch only)
  const float* bl;
  const float* vsrc;
  float* t1p;
  float* psp;
};

template <bool IN_F32>
__global__ __launch_bounds__(256) void gemm_fused(GemmArgs ga) {
  constexpr int LDA = IN_F32 ? 72 : 64;
  __shared__ alignas(16) short SH[64 * 72 + 128 * 64];  // 25600 B
  const int tid = threadIdx.x;

  if (blockIdx.z == 3) {  // ---- vbar1: t1 partials + psum (256 useful blocks)
    const int id2 = blockIdx.y * 128 + blockIdx.x;
    if (id2 >= 256) return;
    float* ek = (float*)SH;
    const int b = id2 >> 6, kb = id2 & 63;
    if (tid < 32) {
      int k = kb * 32 + tid;
      float s = 0.f;
#pragma unroll
      for (int sb = 0; sb < 16; ++sb) s += ga.part[(sb * 4 + b) * 2048 + k];
      float lx = s * 0.001f + ga.bl[k];
      ek[tid] = (ga.mask[b * 2048 + k] == 1) ? 0.f : __expf(lx);
    }
    __syncthreads();
    float a0 = 0.f, a1 = 0.f;
#pragma unroll 4
    for (int kk = 0; kk < 32; ++kk) {
      float e = ek[kk];
      const float* vr = ga.vsrc + (size_t)(b * 2048 + kb * 32 + kk) * 512;
      a0 += e * vr[tid];
      a1 += e * vr[tid + 256];
    }
    ga.t1p[(size_t)id2 * 512 + tid] = a0;
    ga.t1p[(size_t)id2 * 512 + tid + 256] = a1;
    if (tid == 0) {
      float s = 0.f;
      for (int i = 0; i < 32; ++i) s += ek[i];
      ga.psp[id2] = s;
    }
    return;
  }

  short* Al = SH;
  short* Bl = SH + 64 * LDA;
  const int t = blockIdx.z;
  const short* __restrict__ WT = ga.WT[t];
  const float* __restrict__ bias = ga.bias[t];
  const int lane = tid & 63, wid = tid >> 6;
  const int lr = lane & 15, lg = lane >> 4;
  const int wm = wid >> 1, wn = wid & 1;
  // XCD-chunked swizzle (bijective on [0,512))
  const int bid = blockIdx.y * 128 + blockIdx.x;
  const int swz = ((bid & 7) << 6) | (bid >> 3);
  const int m0 = (swz >> 2) * 64, n0 = (swz & 3) * 128;
  const int grow = lane >> 3, gch = lane & 7;

  f32x4 acc[2][4];
#pragma unroll
  for (int i = 0; i < 2; ++i)
#pragma unroll
    for (int j = 0; j < 4; ++j) acc[i][j] = {0.f, 0.f, 0.f, 0.f};

  for (int k0 = 0; k0 < 512; k0 += 64) {
    __syncthreads();
    // ---- stage A
    if constexpr (IN_F32) {
      const float* X = (const float*)ga.X[t];
#pragma unroll
      for (int ii = 0; ii < 4; ++ii) {
        int fidx = tid + ii * 256;
        int row = fidx >> 4, kq = fidx & 15;
        f32x4 vv = *(const f32x4*)(X + (size_t)(m0 + row) * 512 + k0 + kq * 4);
        s16x4 hv = {f2bf(vv[0]), f2bf(vv[1]), f2bf(vv[2]), f2bf(vv[3])};
        *(s16x4*)(&Al[row * 72 + kq * 4]) = hv;
      }
    } else {
      const short* X = (const short*)ga.X[t];
#pragma unroll
      for (int c = 0; c < 2; ++c) {
        int r0 = wid * 16 + c * 8;
        int row = r0 + grow;
        gl_lds16(X + (size_t)(m0 + row) * 512 + k0 + ((gch ^ (row & 7)) << 3),
                 &Al[r0 * 64]);
      }
    }
    // ---- stage B (WT pre-swizzled -> linear direct-to-LDS)
#pragma unroll
    for (int c = 0; c < 4; ++c) {
      int r0 = wid * 32 + c * 8;
      int row = r0 + grow;
      gl_lds16(WT + (size_t)(n0 + row) * 512 + k0 + (gch << 3), &Bl[r0 * 64]);
    }
    __syncthreads();
    // ---- compute
#pragma unroll
    for (int ks = 0; ks < 2; ++ks) {
      s16x8 a[2], bfr[4];
#pragma unroll
      for (int mt = 0; mt < 2; ++mt) {
        int m = wm * 32 + mt * 16 + lr;
        if constexpr (IN_F32)
          a[mt] = *(const s16x8*)(&Al[m * 72 + ks * 32 + lg * 8]);
        else
          a[mt] = *(const s16x8*)(&Al[m * 64 + (((ks * 4 + lg) ^ (m & 7)) << 3)]);
      }
#pragma unroll
      for (int nt = 0; nt < 4; ++nt) {
        int n = wn * 64 + nt * 16 + lr;
        bfr[nt] = *(const s16x8*)(&Bl[n * 64 + (((ks * 4 + lg) ^ (n & 7)) << 3)]);
      }
#pragma unroll
      for (int mt = 0; mt < 2; ++mt)
#pragma unroll
        for (int nt = 0; nt < 4; ++nt)
          acc[mt][nt] = __builtin_amdgcn_mfma_f32_16x16x32_bf16(a[mt], bfr[nt],
                                                                acc[mt][nt], 0, 0, 0);
    }
  }
  // ---- epilogue
  const float os = ga.oscale[t];
  const int mode = ga.mode[t];
  if (mode == 1) {
    // V^T with mask-zeroed columns, via LDS transpose
    __syncthreads();
    short* Tt = SH;  // [128][72]
#pragma unroll
    for (int nt = 0; nt < 4; ++nt) {
      int dl = wn * 64 + nt * 16 + lr;
      float bvv = bias[n0 + dl];
#pragma unroll
      for (int mt = 0; mt < 2; ++mt) {
        int sl = wm * 32 + mt * 16 + lg * 4;
#pragma unroll
        for (int i = 0; i < 4; ++i) {
          float mf = (ga.mask[m0 + sl + i] == 1) ? 0.f : 1.f;
          Tt[dl * 72 + sl + i] = f2bf((acc[mt][nt][i] + bvv) * mf);
        }
      }
    }
    __syncthreads();
    const int dl = tid >> 1, sh = (tid & 1) * 32;
    const int n = n0 + dl;
    const size_t base =
        ((size_t)((m0 >> 11) * 8 + (n >> 6)) * 64 + (n & 63)) * 2048 +
        (m0 & 2047) + sh;
#pragma unroll
    for (int c = 0; c < 4; ++c)
      *(s16x8*)((short*)ga.C[t] + base + c * 8) =
          *(const s16x8*)(&Tt[dl * 72 + sh + c * 8]);
  } else {
#pragma unroll
    for (int nt = 0; nt < 4; ++nt) {
      int col = n0 + wn * 64 + nt * 16 + lr;
      float bvv = bias[col];
#pragma unroll
      for (int mt = 0; mt < 2; ++mt) {
        int r0 = m0 + wm * 32 + mt * 16 + lg * 4;
        if (mode == 2) {
#pragma unroll
          for (int i = 0; i < 4; ++i)
            ((float*)ga.C[t])[(size_t)(r0 + i) * 512 + col] = acc[mt][nt][i] + bvv;
        } else {
#pragma unroll
          for (int i = 0; i < 4; ++i)
            ((short*)ga.C[t])[(size_t)(r0 + i) * 512 + col] =
                f2bf((acc[mt][nt][i] + bvv) * os);
        }
      }
    }
  }
}

// ---------------------------------------------------------------------------
// Flash attention. grid(512) x 256 (4 waves x 32 q-rows; q-tile 128), KV=64.
// Swapped QK^T -> S^T: lane(lr,lg) reg i holds P-value for q=lr,
// kv=nt*16+4lg+i — which IS the A-operand layout of mfma 16x16x16 bf16.
// PV runs as K=16 MFMAs with P packed in registers: NO P LDS round-trip.
// lsum via MFMA vs bf16 mask row. gl_lds dbuf K/V, XOR source swizzle.
// ---------------------------------------------------------------------------
__global__ __launch_bounds__(256) void flash_attn(const short* __restrict__ Qp,
                                                  const short* __restrict__ Kp,
                                                  const short* __restrict__ Vt,
                                                  const int* __restrict__ mask,
                                                  const float* __restrict__ vbar,
                                                  short* __restrict__ concat) {
  constexpr int S = 2048;
  __shared__ alignas(16) short Kl[2][64 * 64];
  __shared__ alignas(16) short Vl[2][64 * 64];
  __shared__ alignas(16) short Mb[2][64];
  const int id = blockIdx.x;
  const int xcd = id & 7, iw = id >> 3;
  const int bh = xcd * 4 + (iw >> 4), qb = iw & 15;
  const int b = bh >> 3, h = bh & 7;
  const int q0 = qb * 128;
  const int tid = threadIdx.x;
  const int lane = tid & 63, wid = tid >> 6;
  const int lr = lane & 15, lg = lane >> 4;

  // staging: 2 slots per thread cover all 64 rows x 8 granules
  const int row0 = tid >> 3, row1 = (tid + 256) >> 3, sg = tid & 7;
  const short* Kg0 = Kp + ((size_t)(b * S) + row0) * 512 + h * 64 + ((sg ^ (row0 & 7)) << 3);
  const short* Kg1 = Kp + ((size_t)(b * S) + row1) * 512 + h * 64 + ((sg ^ (row1 & 7)) << 3);
  const short* Vg0 = Vt + ((size_t)(bh * 64) + row0) * 2048 + ((sg ^ (row0 & 7)) << 3);
  const short* Vg1 = Vt + ((size_t)(bh * 64) + row1) * 2048 + ((sg ^ (row1 & 7)) << 3);

  // prologue: tile 0 -> buf 0
  gl_lds16(Kg0, &Kl[0][tid * 8]);
  gl_lds16(Kg1, &Kl[0][(tid + 256) * 8]);
  gl_lds16(Vg0, &Vl[0][tid * 8]);
  gl_lds16(Vg1, &Vl[0][(tid + 256) * 8]);
  if (tid < 64) Mb[0][tid] = (mask[b * S + tid] == 1) ? (short)0 : (short)0x3F80;

  // Q fragments: 32 q-rows per wave (2 halves of 16)
  const short* Qb0 = Qp + ((size_t)(b * S) + q0 + wid * 32 + lr) * 512 + h * 64;
  s16x8 aq0[2], aq1[2];
#pragma unroll
  for (int qh = 0; qh < 2; ++qh) {
    aq0[qh] = *(const s16x8*)(Qb0 + (size_t)qh * 16 * 512 + lg * 8);
    aq1[qh] = *(const s16x8*)(Qb0 + (size_t)qh * 16 * 512 + 32 + lg * 8);
  }

  f32x4 acc[2][4];
#pragma unroll
  for (int qh = 0; qh < 2; ++qh)
#pragma unroll
    for (int i = 0; i < 4; ++i) acc[qh][i] = {0.f, 0.f, 0.f, 0.f};
  f32x4 accL[2] = {{0.f, 0.f, 0.f, 0.f}, {0.f, 0.f, 0.f, 0.f}};
  const f32x4 zero = {0.f, 0.f, 0.f, 0.f};

  __syncthreads();  // drains tile-0 gl_lds

  int cur = 0;
  for (int t = 0; t < 32; ++t) {
    const int nxt = cur ^ 1;
    int mnxt = 0;
    if (t < 31) {  // issue next-tile loads; hidden under compute
      const size_t kv0n = (size_t)(t + 1) * 64;
      gl_lds16(Kg0 + kv0n * 512, &Kl[nxt][tid * 8]);
      gl_lds16(Kg1 + kv0n * 512, &Kl[nxt][(tid + 256) * 8]);
      gl_lds16(Vg0 + kv0n, &Vl[nxt][tid * 8]);
      gl_lds16(Vg1 + kv0n, &Vl[nxt][(tid + 256) * 8]);
      if (tid < 64) mnxt = mask[b * S + kv0n + tid];
    }
    // ---- QK^T swapped: S^T[kv][q]; K-frags shared by both q-halves
    f32x4 st[2][4];
#pragma unroll
    for (int nt = 0; nt < 4; ++nt) {
      const int rbase = (nt * 16 + lr) * 64;
      s16x8 k0f = *(const s16x8*)(&Kl[cur][rbase + ((lg ^ (lr & 7)) << 3)]);
      s16x8 k1f = *(const s16x8*)(&Kl[cur][rbase + (((4 + lg) ^ (lr & 7)) << 3)]);
#pragma unroll
      for (int qh = 0; qh < 2; ++qh) {
        f32x4 tt = __builtin_amdgcn_mfma_f32_16x16x32_bf16(k0f, aq0[qh], zero, 0, 0, 0);
        st[qh][nt] = __builtin_amdgcn_mfma_f32_16x16x32_bf16(k1f, aq1[qh], tt, 0, 0, 0);
      }
    }
    // ---- PV + lsum via 16x16x16 MFMA; P stays in registers (A-layout match)
#pragma unroll
    for (int nt = 0; nt < 4; ++nt) {
      s16x4 pa0 = {f2bf(fast_exp2(st[0][nt][0])), f2bf(fast_exp2(st[0][nt][1])),
                   f2bf(fast_exp2(st[0][nt][2])), f2bf(fast_exp2(st[0][nt][3]))};
      s16x4 pa1 = {f2bf(fast_exp2(st[1][nt][0])), f2bf(fast_exp2(st[1][nt][1])),
                   f2bf(fast_exp2(st[1][nt][2])), f2bf(fast_exp2(st[1][nt][3]))};
      s16x4 bm = *(const s16x4*)(&Mb[cur][nt * 16 + lg * 4]);
      accL[0] = MFMA16(pa0, bm, accL[0]);
      accL[1] = MFMA16(pa1, bm, accL[1]);
#pragma unroll
      for (int dt = 0; dt < 4; ++dt) {
        const int row = dt * 16 + lr;
        const int gsw = (nt * 2 + (lg >> 1)) ^ (row & 7);
        s16x4 bv = *(const s16x4*)(&Vl[cur][row * 64 + (gsw << 3) + ((lg & 1) << 2)]);
        acc[0][dt] = MFMA16(pa0, bv, acc[0][dt]);
        acc[1][dt] = MFMA16(pa1, bv, acc[1][dt]);
      }
    }
    if (t < 31 && tid < 64)
      Mb[nxt][tid] = (mnxt == 1) ? (short)0 : (short)0x3F80;
    __syncthreads();
    cur = nxt;
  }
  // ---- epilogue: 0.5*acc/accL + 0.5*vbar
#pragma unroll
  for (int qh = 0; qh < 2; ++qh) {
    f32x4 linv;
#pragma unroll
    for (int i = 0; i < 4; ++i) linv[i] = 0.5f / accL[qh][i];
#pragma unroll
    for (int dt = 0; dt < 4; ++dt) {
      int d = dt * 16 + lr;
      float vb = 0.5f * vbar[bh * 64 + d];
#pragma unroll
      for (int i = 0; i < 4; ++i) {
        int q = q0 + wid * 32 + qh * 16 + lg * 4 + i;
        concat[((size_t)(b * S) + q) * 512 + h * 64 + d] =
            f2bf(acc[qh][dt][i] * linv[i] + vb);
      }
    }
  }
}

// ---------------------------------------------------------------------------
extern "C" void kernel_launch(void* const* d_in, const int* in_sizes, int n_in,
                              void* d_out, int out_size, void* d_ws, size_t ws_size,
                              hipStream_t stream) {
  const float* q    = (const float*)d_in[0];
  const float* k    = (const float*)d_in[1];
  const float* v    = (const float*)d_in[2];
  const int*   mask = (const int*)d_in[3];
  const float* Lex  = (const float*)d_in[4];
  const float* Wq   = (const float*)d_in[5];
  const float* bq   = (const float*)d_in[6];
  const float* Wk   = (const float*)d_in[7];
  const float* bk   = (const float*)d_in[8];
  const float* Wv   = (const float*)d_in[9];
  const float* bv   = (const float*)d_in[10];
  const float* Wo   = (const float*)d_in[11];
  const float* bo   = (const float*)d_in[12];
  const float* Wl   = (const float*)d_in[13];
  const float* bl   = (const float*)d_in[14];
  float* out = (float*)d_out;

  char* ws = (char*)d_ws;
  const size_t TSZ = (size_t)8192 * 512 * 2;  // 8.4MB bf16 tensor
  short* Qp  = (short*)(ws);
  short* Kp  = (short*)(ws + TSZ);
  short* Vtp = (short*)(ws + 2 * TSZ);
  short* Cc  = (short*)(ws + 3 * TSZ);
  // scratch aliasing Cc's region (fully consumed before flash writes Cc)
  float* part = (float*)(ws + 3 * TSZ);                  // 512 KB
  float* t1p  = (float*)(ws + 3 * TSZ + (512 << 10));    // 512 KB
  short* WTq = (short*)(ws + 4 * TSZ);
  short* WTk = WTq + 512 * 512;
  short* WTv = WTk + 512 * 512;
  short* WTo = WTv + 512 * 512;
  float* psp   = (float*)(ws + 4 * TSZ + 4 * 512 * 512 * 2);  // 256 f
  float* vbarp = psp + 256;                                   // 2048 f

  PrepArgs pa;
  pa.W[0] = Wq; pa.W[1] = Wk; pa.W[2] = Wv; pa.W[3] = Wo;
  pa.WT[0] = WTq; pa.WT[1] = WTk; pa.WT[2] = WTv; pa.WT[3] = WTo;
  pa.Lex = Lex; pa.Wl = Wl; pa.part = part;
  prep<<<1152, 256, 0, stream>>>(pa);

  GemmArgs gqkv;
  gqkv.X[0] = q;   gqkv.X[1] = k;   gqkv.X[2] = v;
  gqkv.WT[0] = WTq; gqkv.WT[1] = WTk; gqkv.WT[2] = WTv;
  gqkv.bias[0] = bq; gqkv.bias[1] = bk; gqkv.bias[2] = bv;
  gqkv.C[0] = Qp; gqkv.C[1] = Kp; gqkv.C[2] = Vtp;
  gqkv.oscale[0] = QSCALE; gqkv.oscale[1] = 1.f; gqkv.oscale[2] = 1.f;
  gqkv.mode[0] = 0; gqkv.mode[1] = 0; gqkv.mode[2] = 1;
  gqkv.mask = mask;
  gqkv.part = part; gqkv.bl = bl; gqkv.vsrc = v;
  gqkv.t1p = t1p; gqkv.psp = psp;
  gemm_fused<true><<<dim3(128, 4, 4), 256, 0, stream>>>(gqkv);

  vbar2<<<dim3(4, 8), 256, 0, stream>>>(t1p, psp, Wv, bv, vbarp);

  flash_attn<<<512, 256, 0, stream>>>(Qp, Kp, Vtp, mask, vbarp, Cc);

  GemmArgs go;
  go.X[0] = Cc; go.WT[0] = WTo; go.bias[0] = bo; go.C[0] = out;
  go.oscale[0] = 1.f; go.mode[0] = 2;
  go.X[1] = nullptr; go.WT[1] = nullptr; go.bias[1] = nullptr; go.C[1] = nullptr;
  go.X[2] = nullptr; go.WT[2] = nullptr; go.bias[2] = nullptr; go.C[2] = nullptr;
  go.oscale[1] = go.oscale[2] = 1.f; go.mode[1] = go.mode[2] = 0;
  go.mask = mask;
  go.part = nullptr; go.bl = nullptr; go.vsrc = nullptr;
  go.t1p = nullptr; go.psp = nullptr;
  gemm_fused<false><<<dim3(128, 4, 1), 256, 0, stream>>>(go);
}

// Round 13
// 124.065 us; speedup vs baseline: 1.0526x; 1.0526x over previous
//
#include <hip/hip_runtime.h>

// ---------------------------------------------------------------------------
// MultiHeadedAttention: B=4, S=2048, D=512, H=8, DK=64
// 5 dispatches (round-11 GEMMs + 8-wave flash, q-tile 256, grid 256):
//   prep       : WT[n][k] bf16 pre-swizzled (granule^(n&7)) for Wq,Wk,Wv,Wo
//                ++ lex partials
//   qkv (z<3)  : BN=128 gemm, XCD-chunked swizzle
//       (z=3)  : vbar1 = exp(lex-from-part) . v partials + psum partials
//   vbar2      : vbar = (t1@Wv)/tot + bv
//   flash      : 8 waves x 32q (q-tile 256, 1 block/CU); swapped QK^T;
//                P=exp2(st); lsum via MFMA vs bf16 mask row; XOR-swizzled
//                unpadded K/V/P; gl_lds dbuf (staging amortized over 8 waves)
//   gemmO      : out = Cc@Wo + bo (f32), BN=128, XCD swizzle
// ---------------------------------------------------------------------------

typedef __attribute__((ext_vector_type(4))) float f32x4;
typedef __attribute__((ext_vector_type(8))) short s16x8;
typedef __attribute__((ext_vector_type(4))) short s16x4;

#define QSCALE 0.18033688011112042f  // 0.125 * log2(e)

__device__ inline short f2bf(float f) {
  __bf16 h = (__bf16)f;
  return __builtin_bit_cast(short, h);
}
__device__ inline float fast_exp2(float x) {
#if __has_builtin(__builtin_amdgcn_exp2f)
  return __builtin_amdgcn_exp2f(x);
#else
  return exp2f(x);
#endif
}
__device__ inline void gl_lds16(const void* g, void* l) {
  __builtin_amdgcn_global_load_lds(
      (const __attribute__((address_space(1))) void*)g,
      (__attribute__((address_space(3))) void*)l, 16, 0, 0);
}

// ---------------------------------------------------------------------------
// prep: blocks 0..1023 = weight transpose + swizzle; 1024..1151 = lex partials
// ---------------------------------------------------------------------------
struct PrepArgs {
  const float* W[4];
  short* WT[4];
  const float* Lex;
  const float* Wl;
  float* part;
};

__global__ __launch_bounds__(256) void prep(PrepArgs pa) {
  const int blk = blockIdx.x;
  if (blk < 1024) {
    const int z = blk >> 8, tt = blk & 255;
    const float* __restrict__ W = pa.W[z];
    short* __restrict__ WT = pa.WT[z];
    const int n0 = (tt & 15) * 32, k0 = (tt >> 4) * 32;
    const int tx = threadIdx.x & 31, ty = threadIdx.x >> 5;
    __shared__ float Tl[32][33];
#pragma unroll
    for (int j = 0; j < 4; ++j)
      Tl[ty + j * 8][tx] = W[(size_t)(k0 + ty + j * 8) * 512 + n0 + tx];
    __syncthreads();
#pragma unroll
    for (int j = 0; j < 4; ++j) {
      int n = n0 + ty + j * 8, k = k0 + tx;
      int kg = k >> 3;
      int kswz = (((kg & ~7) | ((kg & 7) ^ (n & 7))) << 3) | (k & 7);
      WT[(size_t)n * 512 + kswz] = f2bf(Tl[tx][ty + j * 8]);
    }
  } else {
    const int jb = blk - 1024;
    const int j = (jb & 7) * 256 + threadIdx.x;
    const int sb = jb >> 3, s0 = sb * 128;
    __shared__ float Lsh[4][128];
#pragma unroll
    for (int l = 0; l < 2; ++l) {
      int idx = threadIdx.x + l * 256;
      Lsh[idx >> 7][idx & 127] = pa.Lex[(idx >> 7) * 2048 + s0 + (idx & 127)];
    }
    __syncthreads();
    float a0 = 0.f, a1 = 0.f, a2 = 0.f, a3 = 0.f;
#pragma unroll 4
    for (int si = 0; si < 128; ++si) {
      float w = pa.Wl[(size_t)(s0 + si) * 2048 + j];
      a0 += Lsh[0][si] * w; a1 += Lsh[1][si] * w;
      a2 += Lsh[2][si] * w; a3 += Lsh[3][si] * w;
    }
    pa.part[(sb * 4 + 0) * 2048 + j] = a0;
    pa.part[(sb * 4 + 1) * 2048 + j] = a1;
    pa.part[(sb * 4 + 2) * 2048 + j] = a2;
    pa.part[(sb * 4 + 3) * 2048 + j] = a3;
  }
}

// ---------------------------------------------------------------------------
// vbar2: vbar[b,j] = (t1_b @ Wv)[j]/tot + bv[j].  grid(4,8) x 256
// ---------------------------------------------------------------------------
__global__ __launch_bounds__(256) void vbar2(const float* __restrict__ t1p,
                                             const float* __restrict__ psp,
                                             const float* __restrict__ Wv,
                                             const float* __restrict__ bv,
                                             float* __restrict__ vbar) {
  const int b = blockIdx.x, jb = blockIdx.y, tid = threadIdx.x;
  const int jl = tid & 63, sp = tid >> 6;
  const int j = jb * 64 + jl;
  __shared__ float t1[512];
  __shared__ float red[4][64];
#pragma unroll
  for (int l = 0; l < 2; ++l) {
    int idx = tid + l * 256;
    float s = 0.f;
#pragma unroll 8
    for (int p = 0; p < 64; ++p) s += t1p[(size_t)(b * 64 + p) * 512 + idx];
    t1[idx] = s;
  }
  __syncthreads();
  float a = 0.f;
#pragma unroll 4
  for (int d = sp * 128; d < sp * 128 + 128; ++d) a += t1[d] * Wv[(size_t)d * 512 + j];
  red[sp][jl] = a;
  __syncthreads();
  if (sp == 0) {
    float tot = 0.f;
#pragma unroll 8
    for (int p = 0; p < 64; ++p) tot += psp[b * 64 + p];
    float s = red[0][jl] + red[1][jl] + red[2][jl] + red[3][jl];
    vbar[b * 512 + j] = s / tot + bv[j];
  }
}

// ---------------------------------------------------------------------------
// GEMM: C = X@W + bias, BM=64, BN=128, BK=64; 4 waves 2x2, each 32x64.
// XCD-chunked block swizzle (bijective on [0,512)).
// z<3: tensors; z==3 (QKV launch only): vbar1 partials.
// mode 0: bf16 row-major; 1: bf16 V^T (mask-zeroed); 2: f32 row-major
// ---------------------------------------------------------------------------
struct GemmArgs {
  const void* X[3];
  const short* WT[3];
  const float* bias[3];
  void* C[3];
  float oscale[3];
  int mode[3];
  const int* mask;
  const float* part;   // vbar1 inputs (QKV launch only)
  const float* bl;
  const float* vsrc;
  float* t1p;
  float* psp;
};

template <bool IN_F32>
__global__ __launch_bounds__(256) void gemm_fused(GemmArgs ga) {
  constexpr int LDA = IN_F32 ? 72 : 64;
  __shared__ alignas(16) short SH[64 * 72 + 128 * 64];  // 25600 B
  const int tid = threadIdx.x;

  if (blockIdx.z == 3) {  // ---- vbar1: t1 partials + psum (256 useful blocks)
    const int id2 = blockIdx.y * 128 + blockIdx.x;
    if (id2 >= 256) return;
    float* ek = (float*)SH;
    const int b = id2 >> 6, kb = id2 & 63;
    if (tid < 32) {
      int k = kb * 32 + tid;
      float s = 0.f;
#pragma unroll
      for (int sb = 0; sb < 16; ++sb) s += ga.part[(sb * 4 + b) * 2048 + k];
      float lx = s * 0.001f + ga.bl[k];
      ek[tid] = (ga.mask[b * 2048 + k] == 1) ? 0.f : __expf(lx);
    }
    __syncthreads();
    float a0 = 0.f, a1 = 0.f;
#pragma unroll 4
    for (int kk = 0; kk < 32; ++kk) {
      float e = ek[kk];
      const float* vr = ga.vsrc + (size_t)(b * 2048 + kb * 32 + kk) * 512;
      a0 += e * vr[tid];
      a1 += e * vr[tid + 256];
    }
    ga.t1p[(size_t)id2 * 512 + tid] = a0;
    ga.t1p[(size_t)id2 * 512 + tid + 256] = a1;
    if (tid == 0) {
      float s = 0.f;
      for (int i = 0; i < 32; ++i) s += ek[i];
      ga.psp[id2] = s;
    }
    return;
  }

  short* Al = SH;
  short* Bl = SH + 64 * LDA;
  const int t = blockIdx.z;
  const short* __restrict__ WT = ga.WT[t];
  const float* __restrict__ bias = ga.bias[t];
  const int lane = tid & 63, wid = tid >> 6;
  const int lr = lane & 15, lg = lane >> 4;
  const int wm = wid >> 1, wn = wid & 1;
  // XCD-chunked swizzle (bijective on [0,512))
  const int bid = blockIdx.y * 128 + blockIdx.x;
  const int swz = ((bid & 7) << 6) | (bid >> 3);
  const int m0 = (swz >> 2) * 64, n0 = (swz & 3) * 128;
  const int grow = lane >> 3, gch = lane & 7;

  f32x4 acc[2][4];
#pragma unroll
  for (int i = 0; i < 2; ++i)
#pragma unroll
    for (int j = 0; j < 4; ++j) acc[i][j] = {0.f, 0.f, 0.f, 0.f};

  for (int k0 = 0; k0 < 512; k0 += 64) {
    __syncthreads();
    // ---- stage A
    if constexpr (IN_F32) {
      const float* X = (const float*)ga.X[t];
#pragma unroll
      for (int ii = 0; ii < 4; ++ii) {
        int fidx = tid + ii * 256;
        int row = fidx >> 4, kq = fidx & 15;
        f32x4 vv = *(const f32x4*)(X + (size_t)(m0 + row) * 512 + k0 + kq * 4);
        s16x4 hv = {f2bf(vv[0]), f2bf(vv[1]), f2bf(vv[2]), f2bf(vv[3])};
        *(s16x4*)(&Al[row * 72 + kq * 4]) = hv;
      }
    } else {
      const short* X = (const short*)ga.X[t];
#pragma unroll
      for (int c = 0; c < 2; ++c) {
        int r0 = wid * 16 + c * 8;
        int row = r0 + grow;
        gl_lds16(X + (size_t)(m0 + row) * 512 + k0 + ((gch ^ (row & 7)) << 3),
                 &Al[r0 * 64]);
      }
    }
    // ---- stage B (WT pre-swizzled -> linear direct-to-LDS)
#pragma unroll
    for (int c = 0; c < 4; ++c) {
      int r0 = wid * 32 + c * 8;
      int row = r0 + grow;
      gl_lds16(WT + (size_t)(n0 + row) * 512 + k0 + (gch << 3), &Bl[r0 * 64]);
    }
    __syncthreads();
    // ---- compute
#pragma unroll
    for (int ks = 0; ks < 2; ++ks) {
      s16x8 a[2], bfr[4];
#pragma unroll
      for (int mt = 0; mt < 2; ++mt) {
        int m = wm * 32 + mt * 16 + lr;
        if constexpr (IN_F32)
          a[mt] = *(const s16x8*)(&Al[m * 72 + ks * 32 + lg * 8]);
        else
          a[mt] = *(const s16x8*)(&Al[m * 64 + (((ks * 4 + lg) ^ (m & 7)) << 3)]);
      }
#pragma unroll
      for (int nt = 0; nt < 4; ++nt) {
        int n = wn * 64 + nt * 16 + lr;
        bfr[nt] = *(const s16x8*)(&Bl[n * 64 + (((ks * 4 + lg) ^ (n & 7)) << 3)]);
      }
#pragma unroll
      for (int mt = 0; mt < 2; ++mt)
#pragma unroll
        for (int nt = 0; nt < 4; ++nt)
          acc[mt][nt] = __builtin_amdgcn_mfma_f32_16x16x32_bf16(a[mt], bfr[nt],
                                                                acc[mt][nt], 0, 0, 0);
    }
  }
  // ---- epilogue
  const float os = ga.oscale[t];
  const int mode = ga.mode[t];
  if (mode == 1) {
    // V^T with mask-zeroed columns, via LDS transpose
    __syncthreads();
    short* Tt = SH;  // [128][72]
#pragma unroll
    for (int nt = 0; nt < 4; ++nt) {
      int dl = wn * 64 + nt * 16 + lr;
      float bvv = bias[n0 + dl];
#pragma unroll
      for (int mt = 0; mt < 2; ++mt) {
        int sl = wm * 32 + mt * 16 + lg * 4;
#pragma unroll
        for (int i = 0; i < 4; ++i) {
          float mf = (ga.mask[m0 + sl + i] == 1) ? 0.f : 1.f;
          Tt[dl * 72 + sl + i] = f2bf((acc[mt][nt][i] + bvv) * mf);
        }
      }
    }
    __syncthreads();
    const int dl = tid >> 1, sh = (tid & 1) * 32;
    const int n = n0 + dl;
    const size_t base =
        ((size_t)((m0 >> 11) * 8 + (n >> 6)) * 64 + (n & 63)) * 2048 +
        (m0 & 2047) + sh;
#pragma unroll
    for (int c = 0; c < 4; ++c)
      *(s16x8*)((short*)ga.C[t] + base + c * 8) =
          *(const s16x8*)(&Tt[dl * 72 + sh + c * 8]);
  } else {
#pragma unroll
    for (int nt = 0; nt < 4; ++nt) {
      int col = n0 + wn * 64 + nt * 16 + lr;
      float bvv = bias[col];
#pragma unroll
      for (int mt = 0; mt < 2; ++mt) {
        int r0 = m0 + wm * 32 + mt * 16 + lg * 4;
        if (mode == 2) {
#pragma unroll
          for (int i = 0; i < 4; ++i)
            ((float*)ga.C[t])[(size_t)(r0 + i) * 512 + col] = acc[mt][nt][i] + bvv;
        } else {
#pragma unroll
          for (int i = 0; i < 4; ++i)
            ((short*)ga.C[t])[(size_t)(r0 + i) * 512 + col] =
                f2bf((acc[mt][nt][i] + bvv) * os);
        }
      }
    }
  }
}

// ---------------------------------------------------------------------------
// Flash attention. grid(256) x 512 (8 waves x 32 q-rows; q-tile 256), KV=64.
// 1 block/CU, zero tail. Swapped QK^T -> S^T; K/V frags reused across both
// q-halves; P=exp2(st) unmasked (V cols pre-zeroed); lsum via MFMA vs bf16
// mask row. Unpadded XOR-swizzled K/V/P; gl_lds dbuf (1 K + 1 V slot/thread).
// ---------------------------------------------------------------------------
__global__ __launch_bounds__(512) void flash_attn(const short* __restrict__ Qp,
                                                  const short* __restrict__ Kp,
                                                  const short* __restrict__ Vt,
                                                  const int* __restrict__ mask,
                                                  const float* __restrict__ vbar,
                                                  short* __restrict__ concat) {
  constexpr int S = 2048;
  __shared__ alignas(16) short Kl[2][64 * 64];
  __shared__ alignas(16) short Vl[2][64 * 64];
  __shared__ alignas(16) short Pl[8][32 * 64];
  __shared__ alignas(16) short Mb[2][64];
  const int id = blockIdx.x;
  const int xcd = id & 7, iw = id >> 3;
  const int bh = xcd * 4 + (iw >> 3), qb = iw & 7;
  const int b = bh >> 3, h = bh & 7;
  const int q0 = qb * 256;
  const int tid = threadIdx.x;
  const int lane = tid & 63, wid = tid >> 6;
  const int lr = lane & 15, lg = lane >> 4;

  // staging: 512 threads cover 64 rows x 8 granules, 1 K + 1 V slot each
  const int srow = tid >> 3, sg = tid & 7;
  const int sswz = ((sg ^ (srow & 7)) << 3);
  const short* Kg = Kp + ((size_t)(b * S) + srow) * 512 + h * 64 + sswz;
  const short* Vg = Vt + ((size_t)(bh * 64) + srow) * 2048 + sswz;

  // prologue: tile 0 -> buf 0
  gl_lds16(Kg, &Kl[0][tid * 8]);
  gl_lds16(Vg, &Vl[0][tid * 8]);
  if (tid < 64) Mb[0][tid] = (mask[b * S + tid] == 1) ? (short)0 : (short)0x3F80;

  // Q fragments: 32 q-rows per wave (2 halves of 16)
  const short* Qb0 = Qp + ((size_t)(b * S) + q0 + wid * 32 + lr) * 512 + h * 64;
  s16x8 aq0[2], aq1[2];
#pragma unroll
  for (int qh = 0; qh < 2; ++qh) {
    aq0[qh] = *(const s16x8*)(Qb0 + (size_t)qh * 16 * 512 + lg * 8);
    aq1[qh] = *(const s16x8*)(Qb0 + (size_t)qh * 16 * 512 + 32 + lg * 8);
  }

  f32x4 acc[2][4];
#pragma unroll
  for (int qh = 0; qh < 2; ++qh)
#pragma unroll
    for (int i = 0; i < 4; ++i) acc[qh][i] = {0.f, 0.f, 0.f, 0.f};
  f32x4 accL[2] = {{0.f, 0.f, 0.f, 0.f}, {0.f, 0.f, 0.f, 0.f}};
  const f32x4 zero = {0.f, 0.f, 0.f, 0.f};

  __syncthreads();  // drains tile-0 gl_lds

  int cur = 0;
  for (int t = 0; t < 32; ++t) {
    const int nxt = cur ^ 1;
    int mnxt = 0;
    if (t < 31) {  // issue next-tile loads; hidden under compute
      const size_t kv0n = (size_t)(t + 1) * 64;
      gl_lds16(Kg + kv0n * 512, &Kl[nxt][tid * 8]);
      gl_lds16(Vg + kv0n, &Vl[nxt][tid * 8]);
      if (tid < 64) mnxt = mask[b * S + kv0n + tid];
    }
    // ---- QK^T swapped: S^T[kv][q]; K-frags shared by both q-halves
    f32x4 st[2][4];
#pragma unroll
    for (int nt = 0; nt < 4; ++nt) {
      const int rbase = (nt * 16 + lr) * 64;
      s16x8 k0f = *(const s16x8*)(&Kl[cur][rbase + ((lg ^ (lr & 7)) << 3)]);
      s16x8 k1f = *(const s16x8*)(&Kl[cur][rbase + (((4 + lg) ^ (lr & 7)) << 3)]);
#pragma unroll
      for (int qh = 0; qh < 2; ++qh) {
        f32x4 tt = __builtin_amdgcn_mfma_f32_16x16x32_bf16(k0f, aq0[qh], zero, 0, 0, 0);
        st[qh][nt] = __builtin_amdgcn_mfma_f32_16x16x32_bf16(k1f, aq1[qh], tt, 0, 0, 0);
      }
    }
    // ---- P = exp2(st), swizzled b64 writes into per-wave strip
#pragma unroll
    for (int qh = 0; qh < 2; ++qh) {
      const int prow = (qh * 16 + lr) * 64;
#pragma unroll
      for (int nt = 0; nt < 4; ++nt) {
        float p0 = fast_exp2(st[qh][nt][0]);
        float p1 = fast_exp2(st[qh][nt][1]);
        float p2 = fast_exp2(st[qh][nt][2]);
        float p3 = fast_exp2(st[qh][nt][3]);
        s16x4 pk = {f2bf(p0), f2bf(p1), f2bf(p2), f2bf(p3)};
        int g = nt * 2 + (lg >> 1);
        *(s16x4*)(&Pl[wid][prow + ((g ^ (lr & 7)) << 3) + ((lg & 1) << 2)]) = pk;
      }
    }
    // ---- PV + MFMA lsum; V-frags shared by both q-halves
#pragma unroll
    for (int ks = 0; ks < 2; ++ks) {
      const int fg = (((ks * 4 + lg) ^ (lr & 7)) << 3);
      s16x8 bm = *(const s16x8*)(&Mb[cur][ks * 32 + lg * 8]);
      s16x8 ap[2];
#pragma unroll
      for (int qh = 0; qh < 2; ++qh) {
        ap[qh] = *(const s16x8*)(&Pl[wid][(qh * 16 + lr) * 64 + fg]);
        accL[qh] = __builtin_amdgcn_mfma_f32_16x16x32_bf16(ap[qh], bm, accL[qh], 0, 0, 0);
      }
#pragma unroll
      for (int dt = 0; dt < 4; ++dt) {
        s16x8 bv = *(const s16x8*)(&Vl[cur][(dt * 16 + lr) * 64 + fg]);
#pragma unroll
        for (int qh = 0; qh < 2; ++qh)
          acc[qh][dt] = __builtin_amdgcn_mfma_f32_16x16x32_bf16(ap[qh], bv, acc[qh][dt], 0, 0, 0);
      }
    }
    if (t < 31 && tid < 64)
      Mb[nxt][tid] = (mnxt == 1) ? (short)0 : (short)0x3F80;
    __syncthreads();
    cur = nxt;
  }
  // ---- epilogue: 0.5*acc/accL + 0.5*vbar
#pragma unroll
  for (int qh = 0; qh < 2; ++qh) {
    f32x4 linv;
#pragma unroll
    for (int i = 0; i < 4; ++i) linv[i] = 0.5f / accL[qh][i];
#pragma unroll
    for (int dt = 0; dt < 4; ++dt) {
      int d = dt * 16 + lr;
      float vb = 0.5f * vbar[bh * 64 + d];
#pragma unroll
      for (int i = 0; i < 4; ++i) {
        int q = q0 + wid * 32 + qh * 16 + lg * 4 + i;
        concat[((size_t)(b * S) + q) * 512 + h * 64 + d] =
            f2bf(acc[qh][dt][i] * linv[i] + vb);
      }
    }
  }
}

// ---------------------------------------------------------------------------
extern "C" void kernel_launch(void* const* d_in, const int* in_sizes, int n_in,
                              void* d_out, int out_size, void* d_ws, size_t ws_size,
                              hipStream_t stream) {
  const float* q    = (const float*)d_in[0];
  const float* k    = (const float*)d_in[1];
  const float* v    = (const float*)d_in[2];
  const int*   mask = (const int*)d_in[3];
  const float* Lex  = (const float*)d_in[4];
  const float* Wq   = (const float*)d_in[5];
  const float* bq   = (const float*)d_in[6];
  const float* Wk   = (const float*)d_in[7];
  const float* bk   = (const float*)d_in[8];
  const float* Wv   = (const float*)d_in[9];
  const float* bv   = (const float*)d_in[10];
  const float* Wo   = (const float*)d_in[11];
  const float* bo   = (const float*)d_in[12];
  const float* Wl   = (const float*)d_in[13];
  const float* bl   = (const float*)d_in[14];
  float* out = (float*)d_out;

  char* ws = (char*)d_ws;
  const size_t TSZ = (size_t)8192 * 512 * 2;  // 8.4MB bf16 tensor
  short* Qp  = (short*)(ws);
  short* Kp  = (short*)(ws + TSZ);
  short* Vtp = (short*)(ws + 2 * TSZ);
  short* Cc  = (short*)(ws + 3 * TSZ);
  // scratch aliasing Cc's region (fully consumed before flash writes Cc)
  float* part = (float*)(ws + 3 * TSZ);                  // 512 KB
  float* t1p  = (float*)(ws + 3 * TSZ + (512 << 10));    // 512 KB
  short* WTq = (short*)(ws + 4 * TSZ);
  short* WTk = WTq + 512 * 512;
  short* WTv = WTk + 512 * 512;
  short* WTo = WTv + 512 * 512;
  float* psp   = (float*)(ws + 4 * TSZ + 4 * 512 * 512 * 2);  // 256 f
  float* vbarp = psp + 256;                                   // 2048 f

  PrepArgs pa;
  pa.W[0] = Wq; pa.W[1] = Wk; pa.W[2] = Wv; pa.W[3] = Wo;
  pa.WT[0] = WTq; pa.WT[1] = WTk; pa.WT[2] = WTv; pa.WT[3] = WTo;
  pa.Lex = Lex; pa.Wl = Wl; pa.part = part;
  prep<<<1152, 256, 0, stream>>>(pa);

  GemmArgs gqkv;
  gqkv.X[0] = q;   gqkv.X[1] = k;   gqkv.X[2] = v;
  gqkv.WT[0] = WTq; gqkv.WT[1] = WTk; gqkv.WT[2] = WTv;
  gqkv.bias[0] = bq; gqkv.bias[1] = bk; gqkv.bias[2] = bv;
  gqkv.C[0] = Qp; gqkv.C[1] = Kp; gqkv.C[2] = Vtp;
  gqkv.oscale[0] = QSCALE; gqkv.oscale[1] = 1.f; gqkv.oscale[2] = 1.f;
  gqkv.mode[0] = 0; gqkv.mode[1] = 0; gqkv.mode[2] = 1;
  gqkv.mask = mask;
  gqkv.part = part; gqkv.bl = bl; gqkv.vsrc = v;
  gqkv.t1p = t1p; gqkv.psp = psp;
  gemm_fused<true><<<dim3(128, 4, 4), 256, 0, stream>>>(gqkv);

  vbar2<<<dim3(4, 8), 256, 0, stream>>>(t1p, psp, Wv, bv, vbarp);

  flash_attn<<<256, 512, 0, stream>>>(Qp, Kp, Vtp, mask, vbarp, Cc);

  GemmArgs go;
  go.X[0] = Cc; go.WT[0] = WTo; go.bias[0] = bo; go.C[0] = out;
  go.oscale[0] = 1.f; go.mode[0] = 2;
  go.X[1] = nullptr; go.WT[1] = nullptr; go.bias[1] = nullptr; go.C[1] = nullptr;
  go.X[2] = nullptr; go.WT[2] = nullptr; go.bias[2] = nullptr; go.C[2] = nullptr;
  go.oscale[1] = go.oscale[2] = 1.f; go.mode[1] = go.mode[2] = 0;
  go.mask = mask;
  go.part = nullptr; go.bl = nullptr; go.vsrc = nullptr;
  go.t1p = nullptr; go.psp = nullptr;
  gemm_fused<false><<<dim3(128, 4, 1), 256, 0, stream>>>(go);
}

// Round 14
// 118.542 us; speedup vs baseline: 1.1016x; 1.0466x over previous
//
#include <hip/hip_runtime.h>

// ---------------------------------------------------------------------------
// MultiHeadedAttention: B=4, S=2048, D=512, H=8, DK=64
// 4 dispatches (round-11 + vbar2 folded into flash prologue):
//   prep       : WT[n][k] bf16 pre-swizzled (granule^(n&7)) for Wq,Wk,Wv,Wo
//                ++ lex partials
//   qkv (z<3)  : BN=128 gemm, XCD-chunked swizzle
//       (z=3)  : vbar1 = exp(lex-from-part) . v partials + psum partials
//   flash      : inline vbar=(t1@Wv)/tot+bv in prologue (hidden under tile-0
//                staging); 4 waves x 32q; swapped QK^T; P=exp2(st); lsum via
//                MFMA vs bf16 mask row; XOR-swizzled unpadded K/V/P; gl_lds
//                double-buffer
//   gemmO      : out = Cc@Wo + bo (f32), BN=128, XCD swizzle
// ---------------------------------------------------------------------------

typedef __attribute__((ext_vector_type(4))) float f32x4;
typedef __attribute__((ext_vector_type(8))) short s16x8;
typedef __attribute__((ext_vector_type(4))) short s16x4;

#define QSCALE 0.18033688011112042f  // 0.125 * log2(e)

__device__ inline short f2bf(float f) {
  __bf16 h = (__bf16)f;
  return __builtin_bit_cast(short, h);
}
__device__ inline float fast_exp2(float x) {
#if __has_builtin(__builtin_amdgcn_exp2f)
  return __builtin_amdgcn_exp2f(x);
#else
  return exp2f(x);
#endif
}
__device__ inline void gl_lds16(const void* g, void* l) {
  __builtin_amdgcn_global_load_lds(
      (const __attribute__((address_space(1))) void*)g,
      (__attribute__((address_space(3))) void*)l, 16, 0, 0);
}

// ---------------------------------------------------------------------------
// prep: blocks 0..1023 = weight transpose + swizzle; 1024..1151 = lex partials
// ---------------------------------------------------------------------------
struct PrepArgs {
  const float* W[4];
  short* WT[4];
  const float* Lex;
  const float* Wl;
  float* part;
};

__global__ __launch_bounds__(256) void prep(PrepArgs pa) {
  const int blk = blockIdx.x;
  if (blk < 1024) {
    const int z = blk >> 8, tt = blk & 255;
    const float* __restrict__ W = pa.W[z];
    short* __restrict__ WT = pa.WT[z];
    const int n0 = (tt & 15) * 32, k0 = (tt >> 4) * 32;
    const int tx = threadIdx.x & 31, ty = threadIdx.x >> 5;
    __shared__ float Tl[32][33];
#pragma unroll
    for (int j = 0; j < 4; ++j)
      Tl[ty + j * 8][tx] = W[(size_t)(k0 + ty + j * 8) * 512 + n0 + tx];
    __syncthreads();
#pragma unroll
    for (int j = 0; j < 4; ++j) {
      int n = n0 + ty + j * 8, k = k0 + tx;
      int kg = k >> 3;
      int kswz = (((kg & ~7) | ((kg & 7) ^ (n & 7))) << 3) | (k & 7);
      WT[(size_t)n * 512 + kswz] = f2bf(Tl[tx][ty + j * 8]);
    }
  } else {
    const int jb = blk - 1024;
    const int j = (jb & 7) * 256 + threadIdx.x;
    const int sb = jb >> 3, s0 = sb * 128;
    __shared__ float Lsh[4][128];
#pragma unroll
    for (int l = 0; l < 2; ++l) {
      int idx = threadIdx.x + l * 256;
      Lsh[idx >> 7][idx & 127] = pa.Lex[(idx >> 7) * 2048 + s0 + (idx & 127)];
    }
    __syncthreads();
    float a0 = 0.f, a1 = 0.f, a2 = 0.f, a3 = 0.f;
#pragma unroll 4
    for (int si = 0; si < 128; ++si) {
      float w = pa.Wl[(size_t)(s0 + si) * 2048 + j];
      a0 += Lsh[0][si] * w; a1 += Lsh[1][si] * w;
      a2 += Lsh[2][si] * w; a3 += Lsh[3][si] * w;
    }
    pa.part[(sb * 4 + 0) * 2048 + j] = a0;
    pa.part[(sb * 4 + 1) * 2048 + j] = a1;
    pa.part[(sb * 4 + 2) * 2048 + j] = a2;
    pa.part[(sb * 4 + 3) * 2048 + j] = a3;
  }
}

// ---------------------------------------------------------------------------
// GEMM: C = X@W + bias, BM=64, BN=128, BK=64; 4 waves 2x2, each 32x64.
// XCD-chunked block swizzle (bijective on [0,512)).
// z<3: tensors; z==3 (QKV launch only): vbar1 partials.
// mode 0: bf16 row-major; 1: bf16 V^T (mask-zeroed); 2: f32 row-major
// ---------------------------------------------------------------------------
struct GemmArgs {
  const void* X[3];
  const short* WT[3];
  const float* bias[3];
  void* C[3];
  float oscale[3];
  int mode[3];
  const int* mask;
  const float* part;   // vbar1 inputs (QKV launch only)
  const float* bl;
  const float* vsrc;
  float* t1p;
  float* psp;
};

template <bool IN_F32>
__global__ __launch_bounds__(256) void gemm_fused(GemmArgs ga) {
  constexpr int LDA = IN_F32 ? 72 : 64;
  __shared__ alignas(16) short SH[64 * 72 + 128 * 64];  // 25600 B
  const int tid = threadIdx.x;

  if (blockIdx.z == 3) {  // ---- vbar1: t1 partials + psum (256 useful blocks)
    const int id2 = blockIdx.y * 128 + blockIdx.x;
    if (id2 >= 256) return;
    float* ek = (float*)SH;
    const int b = id2 >> 6, kb = id2 & 63;
    if (tid < 32) {
      int k = kb * 32 + tid;
      float s = 0.f;
#pragma unroll
      for (int sb = 0; sb < 16; ++sb) s += ga.part[(sb * 4 + b) * 2048 + k];
      float lx = s * 0.001f + ga.bl[k];
      ek[tid] = (ga.mask[b * 2048 + k] == 1) ? 0.f : __expf(lx);
    }
    __syncthreads();
    float a0 = 0.f, a1 = 0.f;
#pragma unroll 4
    for (int kk = 0; kk < 32; ++kk) {
      float e = ek[kk];
      const float* vr = ga.vsrc + (size_t)(b * 2048 + kb * 32 + kk) * 512;
      a0 += e * vr[tid];
      a1 += e * vr[tid + 256];
    }
    ga.t1p[(size_t)id2 * 512 + tid] = a0;
    ga.t1p[(size_t)id2 * 512 + tid + 256] = a1;
    if (tid == 0) {
      float s = 0.f;
      for (int i = 0; i < 32; ++i) s += ek[i];
      ga.psp[id2] = s;
    }
    return;
  }

  short* Al = SH;
  short* Bl = SH + 64 * LDA;
  const int t = blockIdx.z;
  const short* __restrict__ WT = ga.WT[t];
  const float* __restrict__ bias = ga.bias[t];
  const int lane = tid & 63, wid = tid >> 6;
  const int lr = lane & 15, lg = lane >> 4;
  const int wm = wid >> 1, wn = wid & 1;
  // XCD-chunked swizzle (bijective on [0,512))
  const int bid = blockIdx.y * 128 + blockIdx.x;
  const int swz = ((bid & 7) << 6) | (bid >> 3);
  const int m0 = (swz >> 2) * 64, n0 = (swz & 3) * 128;
  const int grow = lane >> 3, gch = lane & 7;

  f32x4 acc[2][4];
#pragma unroll
  for (int i = 0; i < 2; ++i)
#pragma unroll
    for (int j = 0; j < 4; ++j) acc[i][j] = {0.f, 0.f, 0.f, 0.f};

  for (int k0 = 0; k0 < 512; k0 += 64) {
    __syncthreads();
    // ---- stage A
    if constexpr (IN_F32) {
      const float* X = (const float*)ga.X[t];
#pragma unroll
      for (int ii = 0; ii < 4; ++ii) {
        int fidx = tid + ii * 256;
        int row = fidx >> 4, kq = fidx & 15;
        f32x4 vv = *(const f32x4*)(X + (size_t)(m0 + row) * 512 + k0 + kq * 4);
        s16x4 hv = {f2bf(vv[0]), f2bf(vv[1]), f2bf(vv[2]), f2bf(vv[3])};
        *(s16x4*)(&Al[row * 72 + kq * 4]) = hv;
      }
    } else {
      const short* X = (const short*)ga.X[t];
#pragma unroll
      for (int c = 0; c < 2; ++c) {
        int r0 = wid * 16 + c * 8;
        int row = r0 + grow;
        gl_lds16(X + (size_t)(m0 + row) * 512 + k0 + ((gch ^ (row & 7)) << 3),
                 &Al[r0 * 64]);
      }
    }
    // ---- stage B (WT pre-swizzled -> linear direct-to-LDS)
#pragma unroll
    for (int c = 0; c < 4; ++c) {
      int r0 = wid * 32 + c * 8;
      int row = r0 + grow;
      gl_lds16(WT + (size_t)(n0 + row) * 512 + k0 + (gch << 3), &Bl[r0 * 64]);
    }
    __syncthreads();
    // ---- compute
#pragma unroll
    for (int ks = 0; ks < 2; ++ks) {
      s16x8 a[2], bfr[4];
#pragma unroll
      for (int mt = 0; mt < 2; ++mt) {
        int m = wm * 32 + mt * 16 + lr;
        if constexpr (IN_F32)
          a[mt] = *(const s16x8*)(&Al[m * 72 + ks * 32 + lg * 8]);
        else
          a[mt] = *(const s16x8*)(&Al[m * 64 + (((ks * 4 + lg) ^ (m & 7)) << 3)]);
      }
#pragma unroll
      for (int nt = 0; nt < 4; ++nt) {
        int n = wn * 64 + nt * 16 + lr;
        bfr[nt] = *(const s16x8*)(&Bl[n * 64 + (((ks * 4 + lg) ^ (n & 7)) << 3)]);
      }
#pragma unroll
      for (int mt = 0; mt < 2; ++mt)
#pragma unroll
        for (int nt = 0; nt < 4; ++nt)
          acc[mt][nt] = __builtin_amdgcn_mfma_f32_16x16x32_bf16(a[mt], bfr[nt],
                                                                acc[mt][nt], 0, 0, 0);
    }
  }
  // ---- epilogue
  const float os = ga.oscale[t];
  const int mode = ga.mode[t];
  if (mode == 1) {
    // V^T with mask-zeroed columns, via LDS transpose
    __syncthreads();
    short* Tt = SH;  // [128][72]
#pragma unroll
    for (int nt = 0; nt < 4; ++nt) {
      int dl = wn * 64 + nt * 16 + lr;
      float bvv = bias[n0 + dl];
#pragma unroll
      for (int mt = 0; mt < 2; ++mt) {
        int sl = wm * 32 + mt * 16 + lg * 4;
#pragma unroll
        for (int i = 0; i < 4; ++i) {
          float mf = (ga.mask[m0 + sl + i] == 1) ? 0.f : 1.f;
          Tt[dl * 72 + sl + i] = f2bf((acc[mt][nt][i] + bvv) * mf);
        }
      }
    }
    __syncthreads();
    const int dl = tid >> 1, sh = (tid & 1) * 32;
    const int n = n0 + dl;
    const size_t base =
        ((size_t)((m0 >> 11) * 8 + (n >> 6)) * 64 + (n & 63)) * 2048 +
        (m0 & 2047) + sh;
#pragma unroll
    for (int c = 0; c < 4; ++c)
      *(s16x8*)((short*)ga.C[t] + base + c * 8) =
          *(const s16x8*)(&Tt[dl * 72 + sh + c * 8]);
  } else {
#pragma unroll
    for (int nt = 0; nt < 4; ++nt) {
      int col = n0 + wn * 64 + nt * 16 + lr;
      float bvv = bias[col];
#pragma unroll
      for (int mt = 0; mt < 2; ++mt) {
        int r0 = m0 + wm * 32 + mt * 16 + lg * 4;
        if (mode == 2) {
#pragma unroll
          for (int i = 0; i < 4; ++i)
            ((float*)ga.C[t])[(size_t)(r0 + i) * 512 + col] = acc[mt][nt][i] + bvv;
        } else {
#pragma unroll
          for (int i = 0; i < 4; ++i)
            ((short*)ga.C[t])[(size_t)(r0 + i) * 512 + col] =
                f2bf((acc[mt][nt][i] + bvv) * os);
        }
      }
    }
  }
}

// ---------------------------------------------------------------------------
// Flash attention. grid(512) x 256 (4 waves x 32 q-rows; q-tile 128), KV=64.
// Inline vbar in prologue (t1p reduce + Wv column dot, Pl as f32 scratch,
// hidden under tile-0 gl_lds). Swapped QK^T -> S^T; K/V frags reused across
// both q-halves; P=exp2(st) unmasked (V cols pre-zeroed); lsum via MFMA vs
// bf16 mask row. Unpadded XOR-swizzled K/V/P; gl_lds dbuf, 2 slots/thread.
// ---------------------------------------------------------------------------
__global__ __launch_bounds__(256) void flash_attn(const short* __restrict__ Qp,
                                                  const short* __restrict__ Kp,
                                                  const short* __restrict__ Vt,
                                                  const int* __restrict__ mask,
                                                  const float* __restrict__ t1p,
                                                  const float* __restrict__ psp,
                                                  const float* __restrict__ Wv,
                                                  const float* __restrict__ bvb,
                                                  short* __restrict__ concat) {
  constexpr int S = 2048;
  __shared__ alignas(16) short Kl[2][64 * 64];
  __shared__ alignas(16) short Vl[2][64 * 64];
  __shared__ alignas(16) short Pl[4][32 * 64];
  __shared__ alignas(16) short Mb[2][64];
  __shared__ float vbar_sh[64];
  const int id = blockIdx.x;
  const int xcd = id & 7, iw = id >> 3;
  const int bh = xcd * 4 + (iw >> 4), qb = iw & 15;
  const int b = bh >> 3, h = bh & 7;
  const int q0 = qb * 128;
  const int tid = threadIdx.x;
  const int lane = tid & 63, wid = tid >> 6;
  const int lr = lane & 15, lg = lane >> 4;

  // staging: 2 slots per thread cover all 64 rows x 8 granules
  const int row0 = tid >> 3, row1 = (tid + 256) >> 3, sg = tid & 7;
  const short* Kg0 = Kp + ((size_t)(b * S) + row0) * 512 + h * 64 + ((sg ^ (row0 & 7)) << 3);
  const short* Kg1 = Kp + ((size_t)(b * S) + row1) * 512 + h * 64 + ((sg ^ (row1 & 7)) << 3);
  const short* Vg0 = Vt + ((size_t)(bh * 64) + row0) * 2048 + ((sg ^ (row0 & 7)) << 3);
  const short* Vg1 = Vt + ((size_t)(bh * 64) + row1) * 2048 + ((sg ^ (row1 & 7)) << 3);

  // prologue: tile 0 -> buf 0 (DMA in flight during vbar computation)
  gl_lds16(Kg0, &Kl[0][tid * 8]);
  gl_lds16(Kg1, &Kl[0][(tid + 256) * 8]);
  gl_lds16(Vg0, &Vl[0][tid * 8]);
  gl_lds16(Vg1, &Vl[0][(tid + 256) * 8]);
  if (tid < 64) Mb[0][tid] = (mask[b * S + tid] == 1) ? (short)0 : (short)0x3F80;

  // ---- inline vbar: t1 = reduce(t1p); vbar = 0.5*((t1@Wv[:,h*64+d])/tot+bv)
  float* t1sh = (float*)&Pl[0][0];  // 512 f (Pl scratch, overwritten in loop)
  float* vpar = t1sh + 512;         // 4*64 f
  {
#pragma unroll
    for (int l = 0; l < 2; ++l) {
      int d = tid + l * 256;
      float s = 0.f;
#pragma unroll 8
      for (int p = 0; p < 64; ++p) s += t1p[(size_t)(b * 64 + p) * 512 + d];
      t1sh[d] = s;
    }
  }
  __syncthreads();
  {
    const int sp = tid >> 6, dl = tid & 63;
    float a = 0.f;
#pragma unroll 8
    for (int dd = sp * 128; dd < sp * 128 + 128; ++dd)
      a += t1sh[dd] * Wv[(size_t)dd * 512 + h * 64 + dl];
    vpar[sp * 64 + dl] = a;
  }
  __syncthreads();
  if (tid < 64) {
    float tot = 0.f;
#pragma unroll 8
    for (int p = 0; p < 64; ++p) tot += psp[b * 64 + p];
    float a = vpar[tid] + vpar[64 + tid] + vpar[128 + tid] + vpar[192 + tid];
    vbar_sh[tid] = 0.5f * (a / tot + bvb[h * 64 + tid]);
  }

  // Q fragments: 32 q-rows per wave (2 halves of 16)
  const short* Qb0 = Qp + ((size_t)(b * S) + q0 + wid * 32 + lr) * 512 + h * 64;
  s16x8 aq0[2], aq1[2];
#pragma unroll
  for (int qh = 0; qh < 2; ++qh) {
    aq0[qh] = *(const s16x8*)(Qb0 + (size_t)qh * 16 * 512 + lg * 8);
    aq1[qh] = *(const s16x8*)(Qb0 + (size_t)qh * 16 * 512 + 32 + lg * 8);
  }

  f32x4 acc[2][4];
#pragma unroll
  for (int qh = 0; qh < 2; ++qh)
#pragma unroll
    for (int i = 0; i < 4; ++i) acc[qh][i] = {0.f, 0.f, 0.f, 0.f};
  f32x4 accL[2] = {{0.f, 0.f, 0.f, 0.f}, {0.f, 0.f, 0.f, 0.f}};
  const f32x4 zero = {0.f, 0.f, 0.f, 0.f};

  __syncthreads();  // drains tile-0 gl_lds; vbar_sh visible

  int cur = 0;
  for (int t = 0; t < 32; ++t) {
    const int nxt = cur ^ 1;
    int mnxt = 0;
    if (t < 31) {  // issue next-tile loads; hidden under compute
      const size_t kv0n = (size_t)(t + 1) * 64;
      gl_lds16(Kg0 + kv0n * 512, &Kl[nxt][tid * 8]);
      gl_lds16(Kg1 + kv0n * 512, &Kl[nxt][(tid + 256) * 8]);
      gl_lds16(Vg0 + kv0n, &Vl[nxt][tid * 8]);
      gl_lds16(Vg1 + kv0n, &Vl[nxt][(tid + 256) * 8]);
      if (tid < 64) mnxt = mask[b * S + kv0n + tid];
    }
    // ---- QK^T swapped: S^T[kv][q]; K-frags shared by both q-halves
    f32x4 st[2][4];
#pragma unroll
    for (int nt = 0; nt < 4; ++nt) {
      const int rbase = (nt * 16 + lr) * 64;
      s16x8 k0f = *(const s16x8*)(&Kl[cur][rbase + ((lg ^ (lr & 7)) << 3)]);
      s16x8 k1f = *(const s16x8*)(&Kl[cur][rbase + (((4 + lg) ^ (lr & 7)) << 3)]);
#pragma unroll
      for (int qh = 0; qh < 2; ++qh) {
        f32x4 tt = __builtin_amdgcn_mfma_f32_16x16x32_bf16(k0f, aq0[qh], zero, 0, 0, 0);
        st[qh][nt] = __builtin_amdgcn_mfma_f32_16x16x32_bf16(k1f, aq1[qh], tt, 0, 0, 0);
      }
    }
    // ---- P = exp2(st), swizzled b64 writes into per-wave strip
#pragma unroll
    for (int qh = 0; qh < 2; ++qh) {
      const int prow = (qh * 16 + lr) * 64;
#pragma unroll
      for (int nt = 0; nt < 4; ++nt) {
        float p0 = fast_exp2(st[qh][nt][0]);
        float p1 = fast_exp2(st[qh][nt][1]);
        float p2 = fast_exp2(st[qh][nt][2]);
        float p3 = fast_exp2(st[qh][nt][3]);
        s16x4 pk = {f2bf(p0), f2bf(p1), f2bf(p2), f2bf(p3)};
        int g = nt * 2 + (lg >> 1);
        *(s16x4*)(&Pl[wid][prow + ((g ^ (lr & 7)) << 3) + ((lg & 1) << 2)]) = pk;
      }
    }
    // ---- PV + MFMA lsum; V-frags shared by both q-halves
#pragma unroll
    for (int ks = 0; ks < 2; ++ks) {
      const int fg = (((ks * 4 + lg) ^ (lr & 7)) << 3);
      s16x8 bm = *(const s16x8*)(&Mb[cur][ks * 32 + lg * 8]);
      s16x8 ap[2];
#pragma unroll
      for (int qh = 0; qh < 2; ++qh) {
        ap[qh] = *(const s16x8*)(&Pl[wid][(qh * 16 + lr) * 64 + fg]);
        accL[qh] = __builtin_amdgcn_mfma_f32_16x16x32_bf16(ap[qh], bm, accL[qh], 0, 0, 0);
      }
#pragma unroll
      for (int dt = 0; dt < 4; ++dt) {
        s16x8 bv = *(const s16x8*)(&Vl[cur][(dt * 16 + lr) * 64 + fg]);
#pragma unroll
        for (int qh = 0; qh < 2; ++qh)
          acc[qh][dt] = __builtin_amdgcn_mfma_f32_16x16x32_bf16(ap[qh], bv, acc[qh][dt], 0, 0, 0);
      }
    }
    if (t < 31 && tid < 64)
      Mb[nxt][tid] = (mnxt == 1) ? (short)0 : (short)0x3F80;
    __syncthreads();
    cur = nxt;
  }
  // ---- epilogue: 0.5*acc/accL + vbar_sh (0.5 pre-applied)
#pragma unroll
  for (int qh = 0; qh < 2; ++qh) {
    f32x4 linv;
#pragma unroll
    for (int i = 0; i < 4; ++i) linv[i] = 0.5f / accL[qh][i];
#pragma unroll
    for (int dt = 0; dt < 4; ++dt) {
      int d = dt * 16 + lr;
      float vb = vbar_sh[d];
#pragma unroll
      for (int i = 0; i < 4; ++i) {
        int q = q0 + wid * 32 + qh * 16 + lg * 4 + i;
        concat[((size_t)(b * S) + q) * 512 + h * 64 + d] =
            f2bf(acc[qh][dt][i] * linv[i] + vb);
      }
    }
  }
}

// ---------------------------------------------------------------------------
extern "C" void kernel_launch(void* const* d_in, const int* in_sizes, int n_in,
                              void* d_out, int out_size, void* d_ws, size_t ws_size,
                              hipStream_t stream) {
  const float* q    = (const float*)d_in[0];
  const float* k    = (const float*)d_in[1];
  const float* v    = (const float*)d_in[2];
  const int*   mask = (const int*)d_in[3];
  const float* Lex  = (const float*)d_in[4];
  const float* Wq   = (const float*)d_in[5];
  const float* bq   = (const float*)d_in[6];
  const float* Wk   = (const float*)d_in[7];
  const float* bk   = (const float*)d_in[8];
  const float* Wv   = (const float*)d_in[9];
  const float* bv   = (const float*)d_in[10];
  const float* Wo   = (const float*)d_in[11];
  const float* bo   = (const float*)d_in[12];
  const float* Wl   = (const float*)d_in[13];
  const float* bl   = (const float*)d_in[14];
  float* out = (float*)d_out;

  char* ws = (char*)d_ws;
  const size_t TSZ = (size_t)8192 * 512 * 2;  // 8.4MB bf16 tensor
  short* Qp  = (short*)(ws);
  short* Kp  = (short*)(ws + TSZ);
  short* Vtp = (short*)(ws + 2 * TSZ);
  short* Cc  = (short*)(ws + 3 * TSZ);
  // part aliases Cc (consumed inside the qkv launch, before flash writes Cc)
  float* part = (float*)(ws + 3 * TSZ);                  // 512 KB
  short* WTq = (short*)(ws + 4 * TSZ);
  short* WTk = WTq + 512 * 512;
  short* WTv = WTk + 512 * 512;
  short* WTo = WTv + 512 * 512;
  // t1p/psp OUTSIDE the Cc alias (flash reads them while writing Cc)
  float* psp = (float*)(ws + 4 * TSZ + 4 * 512 * 512 * 2);  // 256 f
  float* t1p = psp + 1024;                                  // 256*512 f

  PrepArgs pa;
  pa.W[0] = Wq; pa.W[1] = Wk; pa.W[2] = Wv; pa.W[3] = Wo;
  pa.WT[0] = WTq; pa.WT[1] = WTk; pa.WT[2] = WTv; pa.WT[3] = WTo;
  pa.Lex = Lex; pa.Wl = Wl; pa.part = part;
  prep<<<1152, 256, 0, stream>>>(pa);

  GemmArgs gqkv;
  gqkv.X[0] = q;   gqkv.X[1] = k;   gqkv.X[2] = v;
  gqkv.WT[0] = WTq; gqkv.WT[1] = WTk; gqkv.WT[2] = WTv;
  gqkv.bias[0] = bq; gqkv.bias[1] = bk; gqkv.bias[2] = bv;
  gqkv.C[0] = Qp; gqkv.C[1] = Kp; gqkv.C[2] = Vtp;
  gqkv.oscale[0] = QSCALE; gqkv.oscale[1] = 1.f; gqkv.oscale[2] = 1.f;
  gqkv.mode[0] = 0; gqkv.mode[1] = 0; gqkv.mode[2] = 1;
  gqkv.mask = mask;
  gqkv.part = part; gqkv.bl = bl; gqkv.vsrc = v;
  gqkv.t1p = t1p; gqkv.psp = psp;
  gemm_fused<true><<<dim3(128, 4, 4), 256, 0, stream>>>(gqkv);

  flash_attn<<<512, 256, 0, stream>>>(Qp, Kp, Vtp, mask, t1p, psp, Wv, bv, Cc);

  GemmArgs go;
  go.X[0] = Cc; go.WT[0] = WTo; go.bias[0] = bo; go.C[0] = out;
  go.oscale[0] = 1.f; go.mode[0] = 2;
  go.X[1] = nullptr; go.WT[1] = nullptr; go.bias[1] = nullptr; go.C[1] = nullptr;
  go.X[2] = nullptr; go.WT[2] = nullptr; go.bias[2] = nullptr; go.C[2] = nullptr;
  go.oscale[1] = go.oscale[2] = 1.f; go.mode[1] = go.mode[2] = 0;
  go.mask = mask;
  go.part = nullptr; go.bl = nullptr; go.vsrc = nullptr;
  go.t1p = nullptr; go.psp = nullptr;
  gemm_fused<false><<<dim3(128, 4, 1), 256, 0, stream>>>(go);
}

// Round 15
// 115.656 us; speedup vs baseline: 1.1291x; 1.0250x over previous
//
#include <hip/hip_runtime.h>

// ---------------------------------------------------------------------------
// MultiHeadedAttention: B=4, S=2048, D=512, H=8, DK=64
// 4 dispatches (round-14 + 16-partial vbar1 -> 4x smaller flash prologue):
//   prep       : WT[n][k] bf16 pre-swizzled (granule^(n&7)) for Wq,Wk,Wv,Wo
//                ++ lex partials
//   qkv (z<3)  : BN=128 gemm, XCD-chunked swizzle
//       (z=3)  : vbar1 = exp(lex-from-part) . v partials (16/batch) + psum
//   flash      : inline vbar=(t1@Wv)/tot+bv in prologue (16-way reduce,
//                hidden under tile-0 staging); 4 waves x 32q; swapped QK^T;
//                P=exp2(st); lsum via MFMA vs bf16 mask row; XOR-swizzled
//                unpadded K/V/P; gl_lds double-buffer
//   gemmO      : out = Cc@Wo + bo (f32), BN=128, XCD swizzle
// ---------------------------------------------------------------------------

typedef __attribute__((ext_vector_type(4))) float f32x4;
typedef __attribute__((ext_vector_type(8))) short s16x8;
typedef __attribute__((ext_vector_type(4))) short s16x4;

#define QSCALE 0.18033688011112042f  // 0.125 * log2(e)

__device__ inline short f2bf(float f) {
  __bf16 h = (__bf16)f;
  return __builtin_bit_cast(short, h);
}
__device__ inline float fast_exp2(float x) {
#if __has_builtin(__builtin_amdgcn_exp2f)
  return __builtin_amdgcn_exp2f(x);
#else
  return exp2f(x);
#endif
}
__device__ inline void gl_lds16(const void* g, void* l) {
  __builtin_amdgcn_global_load_lds(
      (const __attribute__((address_space(1))) void*)g,
      (__attribute__((address_space(3))) void*)l, 16, 0, 0);
}

// ---------------------------------------------------------------------------
// prep: blocks 0..1023 = weight transpose + swizzle; 1024..1151 = lex partials
// ---------------------------------------------------------------------------
struct PrepArgs {
  const float* W[4];
  short* WT[4];
  const float* Lex;
  const float* Wl;
  float* part;
};

__global__ __launch_bounds__(256) void prep(PrepArgs pa) {
  const int blk = blockIdx.x;
  if (blk < 1024) {
    const int z = blk >> 8, tt = blk & 255;
    const float* __restrict__ W = pa.W[z];
    short* __restrict__ WT = pa.WT[z];
    const int n0 = (tt & 15) * 32, k0 = (tt >> 4) * 32;
    const int tx = threadIdx.x & 31, ty = threadIdx.x >> 5;
    __shared__ float Tl[32][33];
#pragma unroll
    for (int j = 0; j < 4; ++j)
      Tl[ty + j * 8][tx] = W[(size_t)(k0 + ty + j * 8) * 512 + n0 + tx];
    __syncthreads();
#pragma unroll
    for (int j = 0; j < 4; ++j) {
      int n = n0 + ty + j * 8, k = k0 + tx;
      int kg = k >> 3;
      int kswz = (((kg & ~7) | ((kg & 7) ^ (n & 7))) << 3) | (k & 7);
      WT[(size_t)n * 512 + kswz] = f2bf(Tl[tx][ty + j * 8]);
    }
  } else {
    const int jb = blk - 1024;
    const int j = (jb & 7) * 256 + threadIdx.x;
    const int sb = jb >> 3, s0 = sb * 128;
    __shared__ float Lsh[4][128];
#pragma unroll
    for (int l = 0; l < 2; ++l) {
      int idx = threadIdx.x + l * 256;
      Lsh[idx >> 7][idx & 127] = pa.Lex[(idx >> 7) * 2048 + s0 + (idx & 127)];
    }
    __syncthreads();
    float a0 = 0.f, a1 = 0.f, a2 = 0.f, a3 = 0.f;
#pragma unroll 4
    for (int si = 0; si < 128; ++si) {
      float w = pa.Wl[(size_t)(s0 + si) * 2048 + j];
      a0 += Lsh[0][si] * w; a1 += Lsh[1][si] * w;
      a2 += Lsh[2][si] * w; a3 += Lsh[3][si] * w;
    }
    pa.part[(sb * 4 + 0) * 2048 + j] = a0;
    pa.part[(sb * 4 + 1) * 2048 + j] = a1;
    pa.part[(sb * 4 + 2) * 2048 + j] = a2;
    pa.part[(sb * 4 + 3) * 2048 + j] = a3;
  }
}

// ---------------------------------------------------------------------------
// GEMM: C = X@W + bias, BM=64, BN=128, BK=64; 4 waves 2x2, each 32x64.
// XCD-chunked block swizzle (bijective on [0,512)).
// z<3: tensors; z==3 (QKV launch only): vbar1 partials (64 blocks, 128 k).
// mode 0: bf16 row-major; 1: bf16 V^T (mask-zeroed); 2: f32 row-major
// ---------------------------------------------------------------------------
struct GemmArgs {
  const void* X[3];
  const short* WT[3];
  const float* bias[3];
  void* C[3];
  float oscale[3];
  int mode[3];
  const int* mask;
  const float* part;   // vbar1 inputs (QKV launch only)
  const float* bl;
  const float* vsrc;
  float* t1p;
  float* psp;
};

template <bool IN_F32>
__global__ __launch_bounds__(256) void gemm_fused(GemmArgs ga) {
  constexpr int LDA = IN_F32 ? 72 : 64;
  __shared__ alignas(16) short SH[64 * 72 + 128 * 64];  // 25600 B
  const int tid = threadIdx.x;

  if (blockIdx.z == 3) {  // ---- vbar1: 64 useful blocks, 128 k each
    const int id2 = blockIdx.y * 128 + blockIdx.x;
    if (id2 >= 64) return;
    float* ek = (float*)SH;  // 128 f
    const int b = id2 >> 4, kb = id2 & 15;
    if (tid < 128) {
      int k = kb * 128 + tid;
      float s = 0.f;
#pragma unroll
      for (int sb = 0; sb < 16; ++sb) s += ga.part[(sb * 4 + b) * 2048 + k];
      float lx = s * 0.001f + ga.bl[k];
      ek[tid] = (ga.mask[b * 2048 + k] == 1) ? 0.f : __expf(lx);
    }
    __syncthreads();
    float a0 = 0.f, a1 = 0.f;
#pragma unroll 4
    for (int kk = 0; kk < 128; ++kk) {
      float e = ek[kk];
      const float* vr = ga.vsrc + (size_t)(b * 2048 + kb * 128 + kk) * 512;
      a0 += e * vr[tid];
      a1 += e * vr[tid + 256];
    }
    ga.t1p[(size_t)id2 * 512 + tid] = a0;
    ga.t1p[(size_t)id2 * 512 + tid + 256] = a1;
    if (tid == 0) {
      float s = 0.f;
      for (int i = 0; i < 128; ++i) s += ek[i];
      ga.psp[id2] = s;
    }
    return;
  }

  short* Al = SH;
  short* Bl = SH + 64 * LDA;
  const int t = blockIdx.z;
  const short* __restrict__ WT = ga.WT[t];
  const float* __restrict__ bias = ga.bias[t];
  const int lane = tid & 63, wid = tid >> 6;
  const int lr = lane & 15, lg = lane >> 4;
  const int wm = wid >> 1, wn = wid & 1;
  // XCD-chunked swizzle (bijective on [0,512))
  const int bid = blockIdx.y * 128 + blockIdx.x;
  const int swz = ((bid & 7) << 6) | (bid >> 3);
  const int m0 = (swz >> 2) * 64, n0 = (swz & 3) * 128;
  const int grow = lane >> 3, gch = lane & 7;

  f32x4 acc[2][4];
#pragma unroll
  for (int i = 0; i < 2; ++i)
#pragma unroll
    for (int j = 0; j < 4; ++j) acc[i][j] = {0.f, 0.f, 0.f, 0.f};

  for (int k0 = 0; k0 < 512; k0 += 64) {
    __syncthreads();
    // ---- stage A
    if constexpr (IN_F32) {
      const float* X = (const float*)ga.X[t];
#pragma unroll
      for (int ii = 0; ii < 4; ++ii) {
        int fidx = tid + ii * 256;
        int row = fidx >> 4, kq = fidx & 15;
        f32x4 vv = *(const f32x4*)(X + (size_t)(m0 + row) * 512 + k0 + kq * 4);
        s16x4 hv = {f2bf(vv[0]), f2bf(vv[1]), f2bf(vv[2]), f2bf(vv[3])};
        *(s16x4*)(&Al[row * 72 + kq * 4]) = hv;
      }
    } else {
      const short* X = (const short*)ga.X[t];
#pragma unroll
      for (int c = 0; c < 2; ++c) {
        int r0 = wid * 16 + c * 8;
        int row = r0 + grow;
        gl_lds16(X + (size_t)(m0 + row) * 512 + k0 + ((gch ^ (row & 7)) << 3),
                 &Al[r0 * 64]);
      }
    }
    // ---- stage B (WT pre-swizzled -> linear direct-to-LDS)
#pragma unroll
    for (int c = 0; c < 4; ++c) {
      int r0 = wid * 32 + c * 8;
      int row = r0 + grow;
      gl_lds16(WT + (size_t)(n0 + row) * 512 + k0 + (gch << 3), &Bl[r0 * 64]);
    }
    __syncthreads();
    // ---- compute
#pragma unroll
    for (int ks = 0; ks < 2; ++ks) {
      s16x8 a[2], bfr[4];
#pragma unroll
      for (int mt = 0; mt < 2; ++mt) {
        int m = wm * 32 + mt * 16 + lr;
        if constexpr (IN_F32)
          a[mt] = *(const s16x8*)(&Al[m * 72 + ks * 32 + lg * 8]);
        else
          a[mt] = *(const s16x8*)(&Al[m * 64 + (((ks * 4 + lg) ^ (m & 7)) << 3)]);
      }
#pragma unroll
      for (int nt = 0; nt < 4; ++nt) {
        int n = wn * 64 + nt * 16 + lr;
        bfr[nt] = *(const s16x8*)(&Bl[n * 64 + (((ks * 4 + lg) ^ (n & 7)) << 3)]);
      }
#pragma unroll
      for (int mt = 0; mt < 2; ++mt)
#pragma unroll
        for (int nt = 0; nt < 4; ++nt)
          acc[mt][nt] = __builtin_amdgcn_mfma_f32_16x16x32_bf16(a[mt], bfr[nt],
                                                                acc[mt][nt], 0, 0, 0);
    }
  }
  // ---- epilogue
  const float os = ga.oscale[t];
  const int mode = ga.mode[t];
  if (mode == 1) {
    // V^T with mask-zeroed columns, via LDS transpose
    __syncthreads();
    short* Tt = SH;  // [128][72]
#pragma unroll
    for (int nt = 0; nt < 4; ++nt) {
      int dl = wn * 64 + nt * 16 + lr;
      float bvv = bias[n0 + dl];
#pragma unroll
      for (int mt = 0; mt < 2; ++mt) {
        int sl = wm * 32 + mt * 16 + lg * 4;
#pragma unroll
        for (int i = 0; i < 4; ++i) {
          float mf = (ga.mask[m0 + sl + i] == 1) ? 0.f : 1.f;
          Tt[dl * 72 + sl + i] = f2bf((acc[mt][nt][i] + bvv) * mf);
        }
      }
    }
    __syncthreads();
    const int dl = tid >> 1, sh = (tid & 1) * 32;
    const int n = n0 + dl;
    const size_t base =
        ((size_t)((m0 >> 11) * 8 + (n >> 6)) * 64 + (n & 63)) * 2048 +
        (m0 & 2047) + sh;
#pragma unroll
    for (int c = 0; c < 4; ++c)
      *(s16x8*)((short*)ga.C[t] + base + c * 8) =
          *(const s16x8*)(&Tt[dl * 72 + sh + c * 8]);
  } else {
#pragma unroll
    for (int nt = 0; nt < 4; ++nt) {
      int col = n0 + wn * 64 + nt * 16 + lr;
      float bvv = bias[col];
#pragma unroll
      for (int mt = 0; mt < 2; ++mt) {
        int r0 = m0 + wm * 32 + mt * 16 + lg * 4;
        if (mode == 2) {
#pragma unroll
          for (int i = 0; i < 4; ++i)
            ((float*)ga.C[t])[(size_t)(r0 + i) * 512 + col] = acc[mt][nt][i] + bvv;
        } else {
#pragma unroll
          for (int i = 0; i < 4; ++i)
            ((short*)ga.C[t])[(size_t)(r0 + i) * 512 + col] =
                f2bf((acc[mt][nt][i] + bvv) * os);
        }
      }
    }
  }
}

// ---------------------------------------------------------------------------
// Flash attention. grid(512) x 256 (4 waves x 32 q-rows; q-tile 128), KV=64.
// Inline vbar in prologue (16-partial t1p reduce + Wv column dot, Pl as f32
// scratch, hidden under tile-0 gl_lds). Swapped QK^T -> S^T; K/V frags
// reused across both q-halves; P=exp2(st) unmasked (V cols pre-zeroed);
// lsum via MFMA vs bf16 mask row. XOR-swizzled K/V/P; gl_lds dbuf.
// ---------------------------------------------------------------------------
__global__ __launch_bounds__(256) void flash_attn(const short* __restrict__ Qp,
                                                  const short* __restrict__ Kp,
                                                  const short* __restrict__ Vt,
                                                  const int* __restrict__ mask,
                                                  const float* __restrict__ t1p,
                                                  const float* __restrict__ psp,
                                                  const float* __restrict__ Wv,
                                                  const float* __restrict__ bvb,
                                                  short* __restrict__ concat) {
  constexpr int S = 2048;
  __shared__ alignas(16) short Kl[2][64 * 64];
  __shared__ alignas(16) short Vl[2][64 * 64];
  __shared__ alignas(16) short Pl[4][32 * 64];
  __shared__ alignas(16) short Mb[2][64];
  __shared__ float vbar_sh[64];
  const int id = blockIdx.x;
  const int xcd = id & 7, iw = id >> 3;
  const int bh = xcd * 4 + (iw >> 4), qb = iw & 15;
  const int b = bh >> 3, h = bh & 7;
  const int q0 = qb * 128;
  const int tid = threadIdx.x;
  const int lane = tid & 63, wid = tid >> 6;
  const int lr = lane & 15, lg = lane >> 4;

  // staging: 2 slots per thread cover all 64 rows x 8 granules
  const int row0 = tid >> 3, row1 = (tid + 256) >> 3, sg = tid & 7;
  const short* Kg0 = Kp + ((size_t)(b * S) + row0) * 512 + h * 64 + ((sg ^ (row0 & 7)) << 3);
  const short* Kg1 = Kp + ((size_t)(b * S) + row1) * 512 + h * 64 + ((sg ^ (row1 & 7)) << 3);
  const short* Vg0 = Vt + ((size_t)(bh * 64) + row0) * 2048 + ((sg ^ (row0 & 7)) << 3);
  const short* Vg1 = Vt + ((size_t)(bh * 64) + row1) * 2048 + ((sg ^ (row1 & 7)) << 3);

  // prologue: tile 0 -> buf 0 (DMA in flight during vbar computation)
  gl_lds16(Kg0, &Kl[0][tid * 8]);
  gl_lds16(Kg1, &Kl[0][(tid + 256) * 8]);
  gl_lds16(Vg0, &Vl[0][tid * 8]);
  gl_lds16(Vg1, &Vl[0][(tid + 256) * 8]);
  if (tid < 64) Mb[0][tid] = (mask[b * S + tid] == 1) ? (short)0 : (short)0x3F80;

  // ---- inline vbar: t1 = reduce(t1p, 16); vbar = 0.5*((t1@Wv[:,h*64+d])/tot+bv)
  float* t1sh = (float*)&Pl[0][0];  // 512 f (Pl scratch, overwritten in loop)
  float* vpar = t1sh + 512;         // 4*64 f
  {
#pragma unroll
    for (int l = 0; l < 2; ++l) {
      int d = tid + l * 256;
      float s = 0.f;
#pragma unroll
      for (int p = 0; p < 16; ++p) s += t1p[(size_t)(b * 16 + p) * 512 + d];
      t1sh[d] = s;
    }
  }
  __syncthreads();
  {
    const int sp = tid >> 6, dl = tid & 63;
    float a = 0.f;
#pragma unroll 8
    for (int dd = sp * 128; dd < sp * 128 + 128; ++dd)
      a += t1sh[dd] * Wv[(size_t)dd * 512 + h * 64 + dl];
    vpar[sp * 64 + dl] = a;
  }
  __syncthreads();
  if (tid < 64) {
    float tot = 0.f;
#pragma unroll
    for (int p = 0; p < 16; ++p) tot += psp[b * 16 + p];
    float a = vpar[tid] + vpar[64 + tid] + vpar[128 + tid] + vpar[192 + tid];
    vbar_sh[tid] = 0.5f * (a / tot + bvb[h * 64 + tid]);
  }

  // Q fragments: 32 q-rows per wave (2 halves of 16)
  const short* Qb0 = Qp + ((size_t)(b * S) + q0 + wid * 32 + lr) * 512 + h * 64;
  s16x8 aq0[2], aq1[2];
#pragma unroll
  for (int qh = 0; qh < 2; ++qh) {
    aq0[qh] = *(const s16x8*)(Qb0 + (size_t)qh * 16 * 512 + lg * 8);
    aq1[qh] = *(const s16x8*)(Qb0 + (size_t)qh * 16 * 512 + 32 + lg * 8);
  }

  f32x4 acc[2][4];
#pragma unroll
  for (int qh = 0; qh < 2; ++qh)
#pragma unroll
    for (int i = 0; i < 4; ++i) acc[qh][i] = {0.f, 0.f, 0.f, 0.f};
  f32x4 accL[2] = {{0.f, 0.f, 0.f, 0.f}, {0.f, 0.f, 0.f, 0.f}};
  const f32x4 zero = {0.f, 0.f, 0.f, 0.f};

  __syncthreads();  // drains tile-0 gl_lds; vbar_sh visible

  int cur = 0;
  for (int t = 0; t < 32; ++t) {
    const int nxt = cur ^ 1;
    int mnxt = 0;
    if (t < 31) {  // issue next-tile loads; hidden under compute
      const size_t kv0n = (size_t)(t + 1) * 64;
      gl_lds16(Kg0 + kv0n * 512, &Kl[nxt][tid * 8]);
      gl_lds16(Kg1 + kv0n * 512, &Kl[nxt][(tid + 256) * 8]);
      gl_lds16(Vg0 + kv0n, &Vl[nxt][tid * 8]);
      gl_lds16(Vg1 + kv0n, &Vl[nxt][(tid + 256) * 8]);
      if (tid < 64) mnxt = mask[b * S + kv0n + tid];
    }
    // ---- QK^T swapped: S^T[kv][q]; K-frags shared by both q-halves
    f32x4 st[2][4];
#pragma unroll
    for (int nt = 0; nt < 4; ++nt) {
      const int rbase = (nt * 16 + lr) * 64;
      s16x8 k0f = *(const s16x8*)(&Kl[cur][rbase + ((lg ^ (lr & 7)) << 3)]);
      s16x8 k1f = *(const s16x8*)(&Kl[cur][rbase + (((4 + lg) ^ (lr & 7)) << 3)]);
#pragma unroll
      for (int qh = 0; qh < 2; ++qh) {
        f32x4 tt = __builtin_amdgcn_mfma_f32_16x16x32_bf16(k0f, aq0[qh], zero, 0, 0, 0);
        st[qh][nt] = __builtin_amdgcn_mfma_f32_16x16x32_bf16(k1f, aq1[qh], tt, 0, 0, 0);
      }
    }
    // ---- P = exp2(st), swizzled b64 writes into per-wave strip
#pragma unroll
    for (int qh = 0; qh < 2; ++qh) {
      const int prow = (qh * 16 + lr) * 64;
#pragma unroll
      for (int nt = 0; nt < 4; ++nt) {
        float p0 = fast_exp2(st[qh][nt][0]);
        float p1 = fast_exp2(st[qh][nt][1]);
        float p2 = fast_exp2(st[qh][nt][2]);
        float p3 = fast_exp2(st[qh][nt][3]);
        s16x4 pk = {f2bf(p0), f2bf(p1), f2bf(p2), f2bf(p3)};
        int g = nt * 2 + (lg >> 1);
        *(s16x4*)(&Pl[wid][prow + ((g ^ (lr & 7)) << 3) + ((lg & 1) << 2)]) = pk;
      }
    }
    // ---- PV + MFMA lsum; V-frags shared by both q-halves
#pragma unroll
    for (int ks = 0; ks < 2; ++ks) {
      const int fg = (((ks * 4 + lg) ^ (lr & 7)) << 3);
      s16x8 bm = *(const s16x8*)(&Mb[cur][ks * 32 + lg * 8]);
      s16x8 ap[2];
#pragma unroll
      for (int qh = 0; qh < 2; ++qh) {
        ap[qh] = *(const s16x8*)(&Pl[wid][(qh * 16 + lr) * 64 + fg]);
        accL[qh] = __builtin_amdgcn_mfma_f32_16x16x32_bf16(ap[qh], bm, accL[qh], 0, 0, 0);
      }
#pragma unroll
      for (int dt = 0; dt < 4; ++dt) {
        s16x8 bv = *(const s16x8*)(&Vl[cur][(dt * 16 + lr) * 64 + fg]);
#pragma unroll
        for (int qh = 0; qh < 2; ++qh)
          acc[qh][dt] = __builtin_amdgcn_mfma_f32_16x16x32_bf16(ap[qh], bv, acc[qh][dt], 0, 0, 0);
      }
    }
    if (t < 31 && tid < 64)
      Mb[nxt][tid] = (mnxt == 1) ? (short)0 : (short)0x3F80;
    __syncthreads();
    cur = nxt;
  }
  // ---- epilogue: 0.5*acc/accL + vbar_sh (0.5 pre-applied)
#pragma unroll
  for (int qh = 0; qh < 2; ++qh) {
    f32x4 linv;
#pragma unroll
    for (int i = 0; i < 4; ++i) linv[i] = 0.5f / accL[qh][i];
#pragma unroll
    for (int dt = 0; dt < 4; ++dt) {
      int d = dt * 16 + lr;
      float vb = vbar_sh[d];
#pragma unroll
      for (int i = 0; i < 4; ++i) {
        int q = q0 + wid * 32 + qh * 16 + lg * 4 + i;
        concat[((size_t)(b * S) + q) * 512 + h * 64 + d] =
            f2bf(acc[qh][dt][i] * linv[i] + vb);
      }
    }
  }
}

// ---------------------------------------------------------------------------
extern "C" void kernel_launch(void* const* d_in, const int* in_sizes, int n_in,
                              void* d_out, int out_size, void* d_ws, size_t ws_size,
                              hipStream_t stream) {
  const float* q    = (const float*)d_in[0];
  const float* k    = (const float*)d_in[1];
  const float* v    = (const float*)d_in[2];
  const int*   mask = (const int*)d_in[3];
  const float* Lex  = (const float*)d_in[4];
  const float* Wq   = (const float*)d_in[5];
  const float* bq   = (const float*)d_in[6];
  const float* Wk   = (const float*)d_in[7];
  const float* bk   = (const float*)d_in[8];
  const float* Wv   = (const float*)d_in[9];
  const float* bv   = (const float*)d_in[10];
  const float* Wo   = (const float*)d_in[11];
  const float* bo   = (const float*)d_in[12];
  const float* Wl   = (const float*)d_in[13];
  const float* bl   = (const float*)d_in[14];
  float* out = (float*)d_out;

  char* ws = (char*)d_ws;
  const size_t TSZ = (size_t)8192 * 512 * 2;  // 8.4MB bf16 tensor
  short* Qp  = (short*)(ws);
  short* Kp  = (short*)(ws + TSZ);
  short* Vtp = (short*)(ws + 2 * TSZ);
  short* Cc  = (short*)(ws + 3 * TSZ);
  // part aliases Cc (consumed inside the qkv launch, before flash writes Cc)
  float* part = (float*)(ws + 3 * TSZ);                  // 512 KB
  short* WTq = (short*)(ws + 4 * TSZ);
  short* WTk = WTq + 512 * 512;
  short* WTv = WTk + 512 * 512;
  short* WTo = WTv + 512 * 512;
  // t1p/psp OUTSIDE the Cc alias (flash reads them while writing Cc)
  float* psp = (float*)(ws + 4 * TSZ + 4 * 512 * 512 * 2);  // 64 f
  float* t1p = psp + 1024;                                  // 64*512 f

  PrepArgs pa;
  pa.W[0] = Wq; pa.W[1] = Wk; pa.W[2] = Wv; pa.W[3] = Wo;
  pa.WT[0] = WTq; pa.WT[1] = WTk; pa.WT[2] = WTv; pa.WT[3] = WTo;
  pa.Lex = Lex; pa.Wl = Wl; pa.part = part;
  prep<<<1152, 256, 0, stream>>>(pa);

  GemmArgs gqkv;
  gqkv.X[0] = q;   gqkv.X[1] = k;   gqkv.X[2] = v;
  gqkv.WT[0] = WTq; gqkv.WT[1] = WTk; gqkv.WT[2] = WTv;
  gqkv.bias[0] = bq; gqkv.bias[1] = bk; gqkv.bias[2] = bv;
  gqkv.C[0] = Qp; gqkv.C[1] = Kp; gqkv.C[2] = Vtp;
  gqkv.oscale[0] = QSCALE; gqkv.oscale[1] = 1.f; gqkv.oscale[2] = 1.f;
  gqkv.mode[0] = 0; gqkv.mode[1] = 0; gqkv.mode[2] = 1;
  gqkv.mask = mask;
  gqkv.part = part; gqkv.bl = bl; gqkv.vsrc = v;
  gqkv.t1p = t1p; gqkv.psp = psp;
  gemm_fused<true><<<dim3(128, 4, 4), 256, 0, stream>>>(gqkv);

  flash_attn<<<512, 256, 0, stream>>>(Qp, Kp, Vtp, mask, t1p, psp, Wv, bv, Cc);

  GemmArgs go;
  go.X[0] = Cc; go.WT[0] = WTo; go.bias[0] = bo; go.C[0] = out;
  go.oscale[0] = 1.f; go.mode[0] = 2;
  go.X[1] = nullptr; go.WT[1] = nullptr; go.bias[1] = nullptr; go.C[1] = nullptr;
  go.X[2] = nullptr; go.WT[2] = nullptr; go.bias[2] = nullptr; go.C[2] = nullptr;
  go.oscale[1] = go.oscale[2] = 1.f; go.mode[1] = go.mode[2] = 0;
  go.mask = mask;
  go.part = nullptr; go.bl = nullptr; go.vsrc = nullptr;
  go.t1p = nullptr; go.psp = nullptr;
  gemm_fused<false><<<dim3(128, 4, 1), 256, 0, stream>>>(go);
}

// Round 16
// 114.503 us; speedup vs baseline: 1.1405x; 1.0101x over previous
//
#include <hip/hip_runtime.h>

// ---------------------------------------------------------------------------
// MultiHeadedAttention: B=4, S=2048, D=512, H=8, DK=64
// 4 dispatches (round-15 + vectorized flash-prologue vbar):
//   prep       : WT[n][k] bf16 pre-swizzled (granule^(n&7)) for Wq,Wk,Wv,Wo
//                ++ lex partials
//   qkv (z<3)  : BN=128 gemm, XCD-chunked swizzle
//       (z=3)  : vbar1 = exp(lex-from-part) . v partials (16/batch) + psum
//   flash      : inline vbar in prologue: f32x4 t1p reduce + bf16-WTv dot
//                (inverse-swizzle windows); 4 waves x 32q; swapped QK^T;
//                P=exp2(st); lsum via MFMA vs bf16 mask row; XOR-swizzled
//                unpadded K/V/P; gl_lds double-buffer
//   gemmO      : out = Cc@Wo + bo (f32), BN=128, XCD swizzle
// ---------------------------------------------------------------------------

typedef __attribute__((ext_vector_type(4))) float f32x4;
typedef __attribute__((ext_vector_type(8))) short s16x8;
typedef __attribute__((ext_vector_type(4))) short s16x4;

#define QSCALE 0.18033688011112042f  // 0.125 * log2(e)

__device__ inline short f2bf(float f) {
  __bf16 h = (__bf16)f;
  return __builtin_bit_cast(short, h);
}
__device__ inline float bf2f(short h) {
  return __uint_as_float(((unsigned int)(unsigned short)h) << 16);
}
__device__ inline float fast_exp2(float x) {
#if __has_builtin(__builtin_amdgcn_exp2f)
  return __builtin_amdgcn_exp2f(x);
#else
  return exp2f(x);
#endif
}
__device__ inline void gl_lds16(const void* g, void* l) {
  __builtin_amdgcn_global_load_lds(
      (const __attribute__((address_space(1))) void*)g,
      (__attribute__((address_space(3))) void*)l, 16, 0, 0);
}

// ---------------------------------------------------------------------------
// prep: blocks 0..1023 = weight transpose + swizzle; 1024..1151 = lex partials
// ---------------------------------------------------------------------------
struct PrepArgs {
  const float* W[4];
  short* WT[4];
  const float* Lex;
  const float* Wl;
  float* part;
};

__global__ __launch_bounds__(256) void prep(PrepArgs pa) {
  const int blk = blockIdx.x;
  if (blk < 1024) {
    const int z = blk >> 8, tt = blk & 255;
    const float* __restrict__ W = pa.W[z];
    short* __restrict__ WT = pa.WT[z];
    const int n0 = (tt & 15) * 32, k0 = (tt >> 4) * 32;
    const int tx = threadIdx.x & 31, ty = threadIdx.x >> 5;
    __shared__ float Tl[32][33];
#pragma unroll
    for (int j = 0; j < 4; ++j)
      Tl[ty + j * 8][tx] = W[(size_t)(k0 + ty + j * 8) * 512 + n0 + tx];
    __syncthreads();
#pragma unroll
    for (int j = 0; j < 4; ++j) {
      int n = n0 + ty + j * 8, k = k0 + tx;
      int kg = k >> 3;
      int kswz = (((kg & ~7) | ((kg & 7) ^ (n & 7))) << 3) | (k & 7);
      WT[(size_t)n * 512 + kswz] = f2bf(Tl[tx][ty + j * 8]);
    }
  } else {
    const int jb = blk - 1024;
    const int j = (jb & 7) * 256 + threadIdx.x;
    const int sb = jb >> 3, s0 = sb * 128;
    __shared__ float Lsh[4][128];
#pragma unroll
    for (int l = 0; l < 2; ++l) {
      int idx = threadIdx.x + l * 256;
      Lsh[idx >> 7][idx & 127] = pa.Lex[(idx >> 7) * 2048 + s0 + (idx & 127)];
    }
    __syncthreads();
    float a0 = 0.f, a1 = 0.f, a2 = 0.f, a3 = 0.f;
#pragma unroll 4
    for (int si = 0; si < 128; ++si) {
      float w = pa.Wl[(size_t)(s0 + si) * 2048 + j];
      a0 += Lsh[0][si] * w; a1 += Lsh[1][si] * w;
      a2 += Lsh[2][si] * w; a3 += Lsh[3][si] * w;
    }
    pa.part[(sb * 4 + 0) * 2048 + j] = a0;
    pa.part[(sb * 4 + 1) * 2048 + j] = a1;
    pa.part[(sb * 4 + 2) * 2048 + j] = a2;
    pa.part[(sb * 4 + 3) * 2048 + j] = a3;
  }
}

// ---------------------------------------------------------------------------
// GEMM: C = X@W + bias, BM=64, BN=128, BK=64; 4 waves 2x2, each 32x64.
// XCD-chunked block swizzle (bijective on [0,512)).
// z<3: tensors; z==3 (QKV launch only): vbar1 partials (64 blocks, 128 k).
// mode 0: bf16 row-major; 1: bf16 V^T (mask-zeroed); 2: f32 row-major
// ---------------------------------------------------------------------------
struct GemmArgs {
  const void* X[3];
  const short* WT[3];
  const float* bias[3];
  void* C[3];
  float oscale[3];
  int mode[3];
  const int* mask;
  const float* part;   // vbar1 inputs (QKV launch only)
  const float* bl;
  const float* vsrc;
  float* t1p;
  float* psp;
};

template <bool IN_F32>
__global__ __launch_bounds__(256) void gemm_fused(GemmArgs ga) {
  constexpr int LDA = IN_F32 ? 72 : 64;
  __shared__ alignas(16) short SH[64 * 72 + 128 * 64];  // 25600 B
  const int tid = threadIdx.x;

  if (blockIdx.z == 3) {  // ---- vbar1: 64 useful blocks, 128 k each
    const int id2 = blockIdx.y * 128 + blockIdx.x;
    if (id2 >= 64) return;
    float* ek = (float*)SH;  // 128 f
    const int b = id2 >> 4, kb = id2 & 15;
    if (tid < 128) {
      int k = kb * 128 + tid;
      float s = 0.f;
#pragma unroll
      for (int sb = 0; sb < 16; ++sb) s += ga.part[(sb * 4 + b) * 2048 + k];
      float lx = s * 0.001f + ga.bl[k];
      ek[tid] = (ga.mask[b * 2048 + k] == 1) ? 0.f : __expf(lx);
    }
    __syncthreads();
    float a0 = 0.f, a1 = 0.f;
#pragma unroll 4
    for (int kk = 0; kk < 128; ++kk) {
      float e = ek[kk];
      const float* vr = ga.vsrc + (size_t)(b * 2048 + kb * 128 + kk) * 512;
      a0 += e * vr[tid];
      a1 += e * vr[tid + 256];
    }
    ga.t1p[(size_t)id2 * 512 + tid] = a0;
    ga.t1p[(size_t)id2 * 512 + tid + 256] = a1;
    if (tid == 0) {
      float s = 0.f;
      for (int i = 0; i < 128; ++i) s += ek[i];
      ga.psp[id2] = s;
    }
    return;
  }

  short* Al = SH;
  short* Bl = SH + 64 * LDA;
  const int t = blockIdx.z;
  const short* __restrict__ WT = ga.WT[t];
  const float* __restrict__ bias = ga.bias[t];
  const int lane = tid & 63, wid = tid >> 6;
  const int lr = lane & 15, lg = lane >> 4;
  const int wm = wid >> 1, wn = wid & 1;
  // XCD-chunked swizzle (bijective on [0,512))
  const int bid = blockIdx.y * 128 + blockIdx.x;
  const int swz = ((bid & 7) << 6) | (bid >> 3);
  const int m0 = (swz >> 2) * 64, n0 = (swz & 3) * 128;
  const int grow = lane >> 3, gch = lane & 7;

  f32x4 acc[2][4];
#pragma unroll
  for (int i = 0; i < 2; ++i)
#pragma unroll
    for (int j = 0; j < 4; ++j) acc[i][j] = {0.f, 0.f, 0.f, 0.f};

  for (int k0 = 0; k0 < 512; k0 += 64) {
    __syncthreads();
    // ---- stage A
    if constexpr (IN_F32) {
      const float* X = (const float*)ga.X[t];
#pragma unroll
      for (int ii = 0; ii < 4; ++ii) {
        int fidx = tid + ii * 256;
        int row = fidx >> 4, kq = fidx & 15;
        f32x4 vv = *(const f32x4*)(X + (size_t)(m0 + row) * 512 + k0 + kq * 4);
        s16x4 hv = {f2bf(vv[0]), f2bf(vv[1]), f2bf(vv[2]), f2bf(vv[3])};
        *(s16x4*)(&Al[row * 72 + kq * 4]) = hv;
      }
    } else {
      const short* X = (const short*)ga.X[t];
#pragma unroll
      for (int c = 0; c < 2; ++c) {
        int r0 = wid * 16 + c * 8;
        int row = r0 + grow;
        gl_lds16(X + (size_t)(m0 + row) * 512 + k0 + ((gch ^ (row & 7)) << 3),
                 &Al[r0 * 64]);
      }
    }
    // ---- stage B (WT pre-swizzled -> linear direct-to-LDS)
#pragma unroll
    for (int c = 0; c < 4; ++c) {
      int r0 = wid * 32 + c * 8;
      int row = r0 + grow;
      gl_lds16(WT + (size_t)(n0 + row) * 512 + k0 + (gch << 3), &Bl[r0 * 64]);
    }
    __syncthreads();
    // ---- compute
#pragma unroll
    for (int ks = 0; ks < 2; ++ks) {
      s16x8 a[2], bfr[4];
#pragma unroll
      for (int mt = 0; mt < 2; ++mt) {
        int m = wm * 32 + mt * 16 + lr;
        if constexpr (IN_F32)
          a[mt] = *(const s16x8*)(&Al[m * 72 + ks * 32 + lg * 8]);
        else
          a[mt] = *(const s16x8*)(&Al[m * 64 + (((ks * 4 + lg) ^ (m & 7)) << 3)]);
      }
#pragma unroll
      for (int nt = 0; nt < 4; ++nt) {
        int n = wn * 64 + nt * 16 + lr;
        bfr[nt] = *(const s16x8*)(&Bl[n * 64 + (((ks * 4 + lg) ^ (n & 7)) << 3)]);
      }
#pragma unroll
      for (int mt = 0; mt < 2; ++mt)
#pragma unroll
        for (int nt = 0; nt < 4; ++nt)
          acc[mt][nt] = __builtin_amdgcn_mfma_f32_16x16x32_bf16(a[mt], bfr[nt],
                                                                acc[mt][nt], 0, 0, 0);
    }
  }
  // ---- epilogue
  const float os = ga.oscale[t];
  const int mode = ga.mode[t];
  if (mode == 1) {
    // V^T with mask-zeroed columns, via LDS transpose
    __syncthreads();
    short* Tt = SH;  // [128][72]
#pragma unroll
    for (int nt = 0; nt < 4; ++nt) {
      int dl = wn * 64 + nt * 16 + lr;
      float bvv = bias[n0 + dl];
#pragma unroll
      for (int mt = 0; mt < 2; ++mt) {
        int sl = wm * 32 + mt * 16 + lg * 4;
#pragma unroll
        for (int i = 0; i < 4; ++i) {
          float mf = (ga.mask[m0 + sl + i] == 1) ? 0.f : 1.f;
          Tt[dl * 72 + sl + i] = f2bf((acc[mt][nt][i] + bvv) * mf);
        }
      }
    }
    __syncthreads();
    const int dl = tid >> 1, sh = (tid & 1) * 32;
    const int n = n0 + dl;
    const size_t base =
        ((size_t)((m0 >> 11) * 8 + (n >> 6)) * 64 + (n & 63)) * 2048 +
        (m0 & 2047) + sh;
#pragma unroll
    for (int c = 0; c < 4; ++c)
      *(s16x8*)((short*)ga.C[t] + base + c * 8) =
          *(const s16x8*)(&Tt[dl * 72 + sh + c * 8]);
  } else {
#pragma unroll
    for (int nt = 0; nt < 4; ++nt) {
      int col = n0 + wn * 64 + nt * 16 + lr;
      float bvv = bias[col];
#pragma unroll
      for (int mt = 0; mt < 2; ++mt) {
        int r0 = m0 + wm * 32 + mt * 16 + lg * 4;
        if (mode == 2) {
#pragma unroll
          for (int i = 0; i < 4; ++i)
            ((float*)ga.C[t])[(size_t)(r0 + i) * 512 + col] = acc[mt][nt][i] + bvv;
        } else {
#pragma unroll
          for (int i = 0; i < 4; ++i)
            ((short*)ga.C[t])[(size_t)(r0 + i) * 512 + col] =
                f2bf((acc[mt][nt][i] + bvv) * os);
        }
      }
    }
  }
}

// ---------------------------------------------------------------------------
// Flash attention. grid(512) x 256 (4 waves x 32 q-rows; q-tile 128), KV=64.
// Prologue vbar (vectorized): f32x4 t1p reduce + bf16 WTv dot using
// inverse-swizzle contiguous windows (order-free sum); hidden under tile-0
// gl_lds. Main loop identical to round 15.
// ---------------------------------------------------------------------------
__global__ __launch_bounds__(256) void flash_attn(const short* __restrict__ Qp,
                                                  const short* __restrict__ Kp,
                                                  const short* __restrict__ Vt,
                                                  const int* __restrict__ mask,
                                                  const float* __restrict__ t1p,
                                                  const float* __restrict__ psp,
                                                  const short* __restrict__ WTv,
                                                  const float* __restrict__ bvb,
                                                  short* __restrict__ concat) {
  constexpr int S = 2048;
  __shared__ alignas(16) short Kl[2][64 * 64];
  __shared__ alignas(16) short Vl[2][64 * 64];
  __shared__ alignas(16) short Pl[4][32 * 64];
  __shared__ alignas(16) short Mb[2][64];
  __shared__ float vbar_sh[64];
  const int id = blockIdx.x;
  const int xcd = id & 7, iw = id >> 3;
  const int bh = xcd * 4 + (iw >> 4), qb = iw & 15;
  const int b = bh >> 3, h = bh & 7;
  const int q0 = qb * 128;
  const int tid = threadIdx.x;
  const int lane = tid & 63, wid = tid >> 6;
  const int lr = lane & 15, lg = lane >> 4;

  // staging: 2 slots per thread cover all 64 rows x 8 granules
  const int row0 = tid >> 3, row1 = (tid + 256) >> 3, sg = tid & 7;
  const short* Kg0 = Kp + ((size_t)(b * S) + row0) * 512 + h * 64 + ((sg ^ (row0 & 7)) << 3);
  const short* Kg1 = Kp + ((size_t)(b * S) + row1) * 512 + h * 64 + ((sg ^ (row1 & 7)) << 3);
  const short* Vg0 = Vt + ((size_t)(bh * 64) + row0) * 2048 + ((sg ^ (row0 & 7)) << 3);
  const short* Vg1 = Vt + ((size_t)(bh * 64) + row1) * 2048 + ((sg ^ (row1 & 7)) << 3);

  // prologue: tile 0 -> buf 0 (DMA in flight during vbar computation)
  gl_lds16(Kg0, &Kl[0][tid * 8]);
  gl_lds16(Kg1, &Kl[0][(tid + 256) * 8]);
  gl_lds16(Vg0, &Vl[0][tid * 8]);
  gl_lds16(Vg1, &Vl[0][(tid + 256) * 8]);
  if (tid < 64) Mb[0][tid] = (mask[b * S + tid] == 1) ? (short)0 : (short)0x3F80;

  // ---- inline vbar (vectorized)
  float* t1sh = (float*)&Pl[0][0];       // 512 f  (Pl scratch)
  f32x4* tmp4 = (f32x4*)(t1sh + 512);    // 256 f32x4 slots -> 4 KB
  float* vpar = (float*)(tmp4 + 256);    // 256 f
  float tot = 0.f;
#pragma unroll
  for (int p = 0; p < 16; ++p) tot += psp[b * 16 + p];
  {
    const int q4 = tid & 127, half = tid >> 7;
    f32x4 s = {0.f, 0.f, 0.f, 0.f};
#pragma unroll
    for (int p = 0; p < 8; ++p)
      s += *(const f32x4*)(t1p + (size_t)(b * 16 + half * 8 + p) * 512 + q4 * 4);
    tmp4[half * 128 + q4] = s;
  }
  __syncthreads();
  if (tid < 128) {
    f32x4 s = tmp4[tid] + tmp4[128 + tid];
    *(f32x4*)(t1sh + tid * 4) = s;
  }
  __syncthreads();
  {
    // dot over stored (swizzled) WTv windows; each 16B window maps to a
    // contiguous original k-run via the XOR involution -> order-free sum
    const int sp = tid >> 6, dl = tid & 63;
    const int n = h * 64 + dl, nx = n & 7;
    float a = 0.f;
#pragma unroll
    for (int gp = sp * 16; gp < sp * 16 + 16; ++gp) {
      int kg = (gp & ~7) | ((gp & 7) ^ nx);
      s16x8 w = *(const s16x8*)(WTv + (size_t)n * 512 + gp * 8);
#pragma unroll
      for (int e = 0; e < 8; ++e) a += t1sh[kg * 8 + e] * bf2f(w[e]);
    }
    vpar[sp * 64 + dl] = a;
  }
  __syncthreads();
  if (tid < 64) {
    float a = vpar[tid] + vpar[64 + tid] + vpar[128 + tid] + vpar[192 + tid];
    vbar_sh[tid] = 0.5f * (a / tot + bvb[h * 64 + tid]);
  }

  // Q fragments: 32 q-rows per wave (2 halves of 16)
  const short* Qb0 = Qp + ((size_t)(b * S) + q0 + wid * 32 + lr) * 512 + h * 64;
  s16x8 aq0[2], aq1[2];
#pragma unroll
  for (int qh = 0; qh < 2; ++qh) {
    aq0[qh] = *(const s16x8*)(Qb0 + (size_t)qh * 16 * 512 + lg * 8);
    aq1[qh] = *(const s16x8*)(Qb0 + (size_t)qh * 16 * 512 + 32 + lg * 8);
  }

  f32x4 acc[2][4];
#pragma unroll
  for (int qh = 0; qh < 2; ++qh)
#pragma unroll
    for (int i = 0; i < 4; ++i) acc[qh][i] = {0.f, 0.f, 0.f, 0.f};
  f32x4 accL[2] = {{0.f, 0.f, 0.f, 0.f}, {0.f, 0.f, 0.f, 0.f}};
  const f32x4 zero = {0.f, 0.f, 0.f, 0.f};

  __syncthreads();  // drains tile-0 gl_lds; vbar_sh visible; scratch retired

  int cur = 0;
  for (int t = 0; t < 32; ++t) {
    const int nxt = cur ^ 1;
    int mnxt = 0;
    if (t < 31) {  // issue next-tile loads; hidden under compute
      const size_t kv0n = (size_t)(t + 1) * 64;
      gl_lds16(Kg0 + kv0n * 512, &Kl[nxt][tid * 8]);
      gl_lds16(Kg1 + kv0n * 512, &Kl[nxt][(tid + 256) * 8]);
      gl_lds16(Vg0 + kv0n, &Vl[nxt][tid * 8]);
      gl_lds16(Vg1 + kv0n, &Vl[nxt][(tid + 256) * 8]);
      if (tid < 64) mnxt = mask[b * S + kv0n + tid];
    }
    // ---- QK^T swapped: S^T[kv][q]; K-frags shared by both q-halves
    f32x4 st[2][4];
#pragma unroll
    for (int nt = 0; nt < 4; ++nt) {
      const int rbase = (nt * 16 + lr) * 64;
      s16x8 k0f = *(const s16x8*)(&Kl[cur][rbase + ((lg ^ (lr & 7)) << 3)]);
      s16x8 k1f = *(const s16x8*)(&Kl[cur][rbase + (((4 + lg) ^ (lr & 7)) << 3)]);
#pragma unroll
      for (int qh = 0; qh < 2; ++qh) {
        f32x4 tt = __builtin_amdgcn_mfma_f32_16x16x32_bf16(k0f, aq0[qh], zero, 0, 0, 0);
        st[qh][nt] = __builtin_amdgcn_mfma_f32_16x16x32_bf16(k1f, aq1[qh], tt, 0, 0, 0);
      }
    }
    // ---- P = exp2(st), swizzled b64 writes into per-wave strip
#pragma unroll
    for (int qh = 0; qh < 2; ++qh) {
      const int prow = (qh * 16 + lr) * 64;
#pragma unroll
      for (int nt = 0; nt < 4; ++nt) {
        float p0 = fast_exp2(st[qh][nt][0]);
        float p1 = fast_exp2(st[qh][nt][1]);
        float p2 = fast_exp2(st[qh][nt][2]);
        float p3 = fast_exp2(st[qh][nt][3]);
        s16x4 pk = {f2bf(p0), f2bf(p1), f2bf(p2), f2bf(p3)};
        int g = nt * 2 + (lg >> 1);
        *(s16x4*)(&Pl[wid][prow + ((g ^ (lr & 7)) << 3) + ((lg & 1) << 2)]) = pk;
      }
    }
    // ---- PV + MFMA lsum; V-frags shared by both q-halves
#pragma unroll
    for (int ks = 0; ks < 2; ++ks) {
      const int fg = (((ks * 4 + lg) ^ (lr & 7)) << 3);
      s16x8 bm = *(const s16x8*)(&Mb[cur][ks * 32 + lg * 8]);
      s16x8 ap[2];
#pragma unroll
      for (int qh = 0; qh < 2; ++qh) {
        ap[qh] = *(const s16x8*)(&Pl[wid][(qh * 16 + lr) * 64 + fg]);
        accL[qh] = __builtin_amdgcn_mfma_f32_16x16x32_bf16(ap[qh], bm, accL[qh], 0, 0, 0);
      }
#pragma unroll
      for (int dt = 0; dt < 4; ++dt) {
        s16x8 bv = *(const s16x8*)(&Vl[cur][(dt * 16 + lr) * 64 + fg]);
#pragma unroll
        for (int qh = 0; qh < 2; ++qh)
          acc[qh][dt] = __builtin_amdgcn_mfma_f32_16x16x32_bf16(ap[qh], bv, acc[qh][dt], 0, 0, 0);
      }
    }
    if (t < 31 && tid < 64)
      Mb[nxt][tid] = (mnxt == 1) ? (short)0 : (short)0x3F80;
    __syncthreads();
    cur = nxt;
  }
  // ---- epilogue: 0.5*acc/accL + vbar_sh (0.5 pre-applied)
#pragma unroll
  for (int qh = 0; qh < 2; ++qh) {
    f32x4 linv;
#pragma unroll
    for (int i = 0; i < 4; ++i) linv[i] = 0.5f / accL[qh][i];
#pragma unroll
    for (int dt = 0; dt < 4; ++dt) {
      int d = dt * 16 + lr;
      float vb = vbar_sh[d];
#pragma unroll
      for (int i = 0; i < 4; ++i) {
        int q = q0 + wid * 32 + qh * 16 + lg * 4 + i;
        concat[((size_t)(b * S) + q) * 512 + h * 64 + d] =
            f2bf(acc[qh][dt][i] * linv[i] + vb);
      }
    }
  }
}

// ---------------------------------------------------------------------------
extern "C" void kernel_launch(void* const* d_in, const int* in_sizes, int n_in,
                              void* d_out, int out_size, void* d_ws, size_t ws_size,
                              hipStream_t stream) {
  const float* q    = (const float*)d_in[0];
  const float* k    = (const float*)d_in[1];
  const float* v    = (const float*)d_in[2];
  const int*   mask = (const int*)d_in[3];
  const float* Lex  = (const float*)d_in[4];
  const float* Wq   = (const float*)d_in[5];
  const float* bq   = (const float*)d_in[6];
  const float* Wk   = (const float*)d_in[7];
  const float* bk   = (const float*)d_in[8];
  const float* Wv   = (const float*)d_in[9];
  const float* bv   = (const float*)d_in[10];
  const float* Wo   = (const float*)d_in[11];
  const float* bo   = (const float*)d_in[12];
  const float* Wl   = (const float*)d_in[13];
  const float* bl   = (const float*)d_in[14];
  float* out = (float*)d_out;

  char* ws = (char*)d_ws;
  const size_t TSZ = (size_t)8192 * 512 * 2;  // 8.4MB bf16 tensor
  short* Qp  = (short*)(ws);
  short* Kp  = (short*)(ws + TSZ);
  short* Vtp = (short*)(ws + 2 * TSZ);
  short* Cc  = (short*)(ws + 3 * TSZ);
  // part aliases Cc (consumed inside the qkv launch, before flash writes Cc)
  float* part = (float*)(ws + 3 * TSZ);                  // 512 KB
  short* WTq = (short*)(ws + 4 * TSZ);
  short* WTk = WTq + 512 * 512;
  short* WTv = WTk + 512 * 512;
  short* WTo = WTv + 512 * 512;
  // t1p/psp OUTSIDE the Cc alias (flash reads them while writing Cc)
  float* psp = (float*)(ws + 4 * TSZ + 4 * 512 * 512 * 2);  // 64 f
  float* t1p = psp + 1024;                                  // 64*512 f

  PrepArgs pa;
  pa.W[0] = Wq; pa.W[1] = Wk; pa.W[2] = Wv; pa.W[3] = Wo;
  pa.WT[0] = WTq; pa.WT[1] = WTk; pa.WT[2] = WTv; pa.WT[3] = WTo;
  pa.Lex = Lex; pa.Wl = Wl; pa.part = part;
  prep<<<1152, 256, 0, stream>>>(pa);

  GemmArgs gqkv;
  gqkv.X[0] = q;   gqkv.X[1] = k;   gqkv.X[2] = v;
  gqkv.WT[0] = WTq; gqkv.WT[1] = WTk; gqkv.WT[2] = WTv;
  gqkv.bias[0] = bq; gqkv.bias[1] = bk; gqkv.bias[2] = bv;
  gqkv.C[0] = Qp; gqkv.C[1] = Kp; gqkv.C[2] = Vtp;
  gqkv.oscale[0] = QSCALE; gqkv.oscale[1] = 1.f; gqkv.oscale[2] = 1.f;
  gqkv.mode[0] = 0; gqkv.mode[1] = 0; gqkv.mode[2] = 1;
  gqkv.mask = mask;
  gqkv.part = part; gqkv.bl = bl; gqkv.vsrc = v;
  gqkv.t1p = t1p; gqkv.psp = psp;
  gemm_fused<true><<<dim3(128, 4, 4), 256, 0, stream>>>(gqkv);

  flash_attn<<<512, 256, 0, stream>>>(Qp, Kp, Vtp, mask, t1p, psp, WTv, bv, Cc);

  GemmArgs go;
  go.X[0] = Cc; go.WT[0] = WTo; go.bias[0] = bo; go.C[0] = out;
  go.oscale[0] = 1.f; go.mode[0] = 2;
  go.X[1] = nullptr; go.WT[1] = nullptr; go.bias[1] = nullptr; go.C[1] = nullptr;
  go.X[2] = nullptr; go.WT[2] = nullptr; go.bias[2] = nullptr; go.C[2] = nullptr;
  go.oscale[1] = go.oscale[2] = 1.f; go.mode[1] = go.mode[2] = 0;
  go.mask = mask;
  go.part = nullptr; go.bl = nullptr; go.vsrc = nullptr;
  go.t1p = nullptr; go.psp = nullptr;
  gemm_fused<false><<<dim3(128, 4, 1), 256, 0, stream>>>(go);
}